// Round 10
// baseline (117.540 us; speedup 1.0000x reference)
//
#include <hip/hip_runtime.h>
#include <math.h>

#define NB 4
#define TTEXT 160
#define TFEAT 800

typedef __bf16 bf16x8 __attribute__((ext_vector_type(8)));
typedef float f32x4 __attribute__((ext_vector_type(4)));
typedef unsigned short us8 __attribute__((ext_vector_type(8)));

__device__ inline unsigned short f2bf(float f) {
    unsigned int u = __builtin_bit_cast(unsigned int, f);
    unsigned int r = u + 0x7fffu + ((u >> 16) & 1u);
    return (unsigned short)(r >> 16);
}
__device__ inline float bf2f(unsigned short h) {
    unsigned int u = ((unsigned int)h) << 16;
    return __builtin_bit_cast(float, u);
}

// f32 lgamma for integer arguments n>=1 (Stirling, n<8 promoted by 8).
__device__ inline float lgamma_int(float nf) {
    float z = nf, corr = 0.0f;
    if (nf < 8.0f) {
        const float p = nf * (nf + 1.0f) * (nf + 2.0f) * (nf + 3.0f)
                      * (nf + 4.0f) * (nf + 5.0f) * (nf + 6.0f) * (nf + 7.0f);
        z = nf + 8.0f;
        corr = logf(p);
    }
    const float lz = logf(z);
    const float iz = 1.0f / z;
    const float s = (z - 0.5f) * lz - z + 0.918938533f
                  + iz * (0.0833333333f - iz * iz * 0.00277777778f);
    return s - corr;
}

// ---------------------------------------------------------------------------
// K1: blocks 0..39  = text stem (16 waves, weights read INLINE from original
//                     f32 layout: K=3 -> stride-3 gather, K=1 -> contiguous
//                     float4; same f2bf conversion => bit-identical math).
//     blocks 40..367 = feats weight transform (exact 328x1024 flat map) into
//                     B-fragment-native layout Wb[c][co][q].
// No cross-block dependencies inside this kernel.
// ---------------------------------------------------------------------------
__global__ __launch_bounds__(1024) void k1_text_prep(
    const float* __restrict__ text,
    const float* __restrict__ t_w1, const float* __restrict__ t_b1,
    const float* __restrict__ t_w2, const float* __restrict__ t_b2,
    const float* __restrict__ f_w1, const float* __restrict__ f_w2,
    const float* __restrict__ f_w3,
    unsigned short* __restrict__ wb_f1, unsigned short* __restrict__ wb_f2,
    unsigned short* __restrict__ wb_f3,
    unsigned short* __restrict__ tB, float* __restrict__ tnorm)
{
    const int bid = blockIdx.x;
    const int tid = threadIdx.x;

    if (bid >= 40) {
        // ---------------- feats weight transform ----------------
        const int u = (bid - 40) * 1024 + tid;   // [0, 335872) exactly
        int rem = u;
        int CIN, CINP, K; const float* src; unsigned short* dst;
        if (rem < 73728)                  { CIN = 80;  CINP = 96;  K = 3; src = f_w1; dst = wb_f1; }
        else if ((rem -= 73728) < 196608) { CIN = 256; CINP = 256; K = 3; src = f_w2; dst = wb_f2; }
        else { rem -= 196608;               CIN = 256; CINP = 256; K = 1; src = f_w3; dst = wb_f3; }
        const int q = rem & 31, coc = rem >> 5, co = coc & 255, c = coc >> 8;
        const int cpk = CINP / 32, k = c / cpk, ci = (c % cpk) * 32 + q;
        const float v = (ci < CIN) ? src[((size_t)co * CIN + ci) * K + k] : 0.0f;
        dst[rem] = f2bf(v);
        return;
    }

    // ---------------- text stem (16 waves, inline f32 weights) --------------
    __shared__ __align__(16) unsigned short s[8976];   // s_in 18*264 + s_mid 16*264
    __shared__ float s_red[16][16];
    const int w  = tid >> 6;        // 0..15
    const int l  = tid & 63;
    const int lr = l & 15;
    const int lk = l >> 4;
    const int co0 = w * 16;
    const int koff = lk * 8;
    const int b  = bid & 3;
    const int t0 = (bid >> 2) << 4;
    unsigned short* s_in  = s;          // [18][264]
    unsigned short* s_mid = s + 4752;   // [16][264]

    for (int idx = tid; idx < 18 * 64; idx += 1024) {
        const int r = idx >> 6, c4 = idx & 63;
        const int x = t0 - 1 + r;
        float4 v = {0.f, 0.f, 0.f, 0.f};
        if (x >= 0 && x < TTEXT)
            v = *(const float4*)(text + ((size_t)(b * TTEXT + x)) * 256 + c4 * 4);
        unsigned short* p = s_in + r * 264 + c4 * 4;
        p[0] = f2bf(v.x); p[1] = f2bf(v.y); p[2] = f2bf(v.z); p[3] = f2bf(v.w);
    }
    __syncthreads();

    // t1: K=3, CIN=256 -> 24 chunks; weight fragment = 8 f32 stride-3 gather
    f32x4 acc = {0.f, 0.f, 0.f, 0.f};
#pragma unroll 4
    for (int c = 0; c < 24; ++c) {
        const int k  = c >> 3;
        const int ci = ((c & 7) << 5) + koff;
        const bf16x8 a = *(const bf16x8*)(s_in + (lr + k) * 264 + ci);
        const float* wp = t_w1 + ((size_t)(co0 + lr) * 256 + ci) * 3 + k;
        us8 hv;
#pragma unroll
        for (int j = 0; j < 8; ++j) hv[j] = f2bf(wp[j * 3]);
        acc = __builtin_amdgcn_mfma_f32_16x16x32_bf16(
            a, __builtin_bit_cast(bf16x8, hv), acc, 0, 0, 0);
    }
    {
        const float bv = t_b1[co0 + lr];
#pragma unroll
        for (int r = 0; r < 4; ++r)
            s_mid[(lk * 4 + r) * 264 + co0 + lr] = f2bf(fmaxf(acc[r] + bv, 0.f));
    }
    __syncthreads();

    // t2: K=1 -> 8 chunks; weight fragment = 8 contiguous f32 (two float4)
    f32x4 a2 = {0.f, 0.f, 0.f, 0.f};
#pragma unroll
    for (int c = 0; c < 8; ++c) {
        const bf16x8 a = *(const bf16x8*)(s_mid + lr * 264 + (c << 5) + koff);
        const float* wp = t_w2 + (size_t)(co0 + lr) * 256 + (c << 5) + koff;
        const float4 u0 = *(const float4*)wp;
        const float4 u1 = *(const float4*)(wp + 4);
        us8 hv;
        hv[0] = f2bf(u0.x); hv[1] = f2bf(u0.y); hv[2] = f2bf(u0.z); hv[3] = f2bf(u0.w);
        hv[4] = f2bf(u1.x); hv[5] = f2bf(u1.y); hv[6] = f2bf(u1.z); hv[7] = f2bf(u1.w);
        a2 = __builtin_amdgcn_mfma_f32_16x16x32_bf16(
            a, __builtin_bit_cast(bf16x8, hv), a2, 0, 0, 0);
    }
    const float bv2 = t_b2[co0 + lr];
#pragma unroll
    for (int r = 0; r < 4; ++r) {
        const int row = lk * 4 + r;
        const unsigned short h = f2bf(a2[r] + bv2);
        tB[((size_t)(b * TTEXT + t0 + row)) * 256 + co0 + lr] = h;
        const float vq = bf2f(h);
        float np = vq * vq;
        np += __shfl_xor(np, 1);
        np += __shfl_xor(np, 2);
        np += __shfl_xor(np, 4);
        np += __shfl_xor(np, 8);
        if (lr == 0) s_red[row][w] = np;
    }
    __syncthreads();
    if (tid < 16) {
        float s4 = 0.f;
#pragma unroll
        for (int ww = 0; ww < 16; ++ww) s4 += s_red[tid][ww];
        tnorm[b * TTEXT + t0 + tid] = s4;
    }
}

// ---------------------------------------------------------------------------
// K2: feats stem (verified 16-wave round-9 code; f3 output + norms stay in
// LDS) + fused score phase (wave w<10 owns N-frag w; 2-barrier LDS softmax;
// LDS Stirling-lgamma table). 200 blocks x 1024 threads.
// ---------------------------------------------------------------------------
__global__ __launch_bounds__(1024) void k2_feats_score(
    const float* __restrict__ feats, const unsigned char* __restrict__ xmask,
    const unsigned short* __restrict__ wf1, const float* __restrict__ bf1v,
    const unsigned short* __restrict__ wf2, const float* __restrict__ bf2v,
    const unsigned short* __restrict__ wf3, const float* __restrict__ bf3v,
    const unsigned short* __restrict__ tB, const float* __restrict__ tnorm,
    float* __restrict__ out)
{
    __shared__ __align__(16) unsigned short s[11056];
    __shared__ float s_red[16][16];
    __shared__ float s_red2[16][16];
    __shared__ float s_fn[16];
    __shared__ float s_lg[962];
    const int tid = threadIdx.x;
    const int w  = tid >> 6;        // 0..15
    const int l  = tid & 63;
    const int lr = l & 15;
    const int lk = l >> 4;
    const int co0 = w * 16;
    const int koff = lk * 8;
    const int fb = blockIdx.x;
    const int b  = fb & 3;
    const int t0 = (fb >> 2) << 4;

    unsigned short* s_fin = s;          // [20][104]
    unsigned short* s_b1  = s + 2080;   // [18][264]
    unsigned short* s_b2  = s + 6832;   // [16][264]
    unsigned short* s_out = s;          // [16][264] overlays s_fin/s_b1 (dead after f2)

    // lgamma table (used only after several barriers)
    if (tid < 962) s_lg[tid] = (tid >= 1) ? lgamma_int((float)tid) : 0.0f;

    for (int idx = tid; idx < 20 * 24; idx += 1024) {
        const int r  = idx / 24, c4 = idx - r * 24;
        const int ch = c4 * 4;
        const int x  = t0 - 2 + r;
        float4 v = {0.f, 0.f, 0.f, 0.f};
        if (ch < 80 && x >= 0 && x < TFEAT)
            v = *(const float4*)(feats + ((size_t)(b * TFEAT + x)) * 80 + ch);
        unsigned short* p = s_fin + r * 104 + ch;
        p[0] = f2bf(v.x); p[1] = f2bf(v.y); p[2] = f2bf(v.z); p[3] = f2bf(v.w);
    }
    __syncthreads();

    // f1: K=3, CINP=96 -> 9 chunks; 18 output rows (2 M-frags, masked)
    f32x4 acc1[2];
#pragma unroll
    for (int m = 0; m < 2; ++m) acc1[m] = {0.f, 0.f, 0.f, 0.f};
#pragma unroll
    for (int c = 0; c < 9; ++c) {
        const int k  = c / 3;
        const int ci = (c - k * 3) * 32 + koff;
        const bf16x8 bb = *(const bf16x8*)(wf1 + (((size_t)c * 256 + co0 + lr) << 5) + koff);
#pragma unroll
        for (int m = 0; m < 2; ++m) {
            int rr = m * 16 + lr + k;
            if (rr > 19) rr = 19;   // clamp; rows >=18 masked at write
            const bf16x8 a = *(const bf16x8*)(s_fin + rr * 104 + ci);
            acc1[m] = __builtin_amdgcn_mfma_f32_16x16x32_bf16(a, bb, acc1[m], 0, 0, 0);
        }
    }
    {
        const float bv = bf1v[co0 + lr];
#pragma unroll
        for (int m = 0; m < 2; ++m)
#pragma unroll
            for (int r = 0; r < 4; ++r) {
                const int i = m * 16 + lk * 4 + r;
                if (i < 18)
                    s_b1[i * 264 + co0 + lr] = f2bf(fmaxf(acc1[m][r] + bv, 0.f));
            }
    }
    __syncthreads();

    // f2: K=3, CIN=256 -> 24 chunks
    f32x4 acc2 = {0.f, 0.f, 0.f, 0.f};
#pragma unroll 8
    for (int c = 0; c < 24; ++c) {
        const int k  = c >> 3;
        const int ci = ((c & 7) << 5) + koff;
        const bf16x8 a = *(const bf16x8*)(s_b1 + (lr + k) * 264 + ci);
        const bf16x8 bb = *(const bf16x8*)(wf2 + (((size_t)c * 256 + co0 + lr) << 5) + koff);
        acc2 = __builtin_amdgcn_mfma_f32_16x16x32_bf16(a, bb, acc2, 0, 0, 0);
    }
    {
        const float bv = bf2v[co0 + lr];
#pragma unroll
        for (int r = 0; r < 4; ++r)
            s_b2[(lk * 4 + r) * 264 + co0 + lr] = f2bf(fmaxf(acc2[r] + bv, 0.f));
    }
    __syncthreads();

    // f3: K=1 -> 8 chunks; output -> LDS s_out, norms -> s_fn
    f32x4 a3 = {0.f, 0.f, 0.f, 0.f};
#pragma unroll
    for (int c = 0; c < 8; ++c) {
        const bf16x8 a = *(const bf16x8*)(s_b2 + lr * 264 + (c << 5) + koff);
        const bf16x8 bb = *(const bf16x8*)(wf3 + (((size_t)c * 256 + co0 + lr) << 5) + koff);
        a3 = __builtin_amdgcn_mfma_f32_16x16x32_bf16(a, bb, a3, 0, 0, 0);
    }
    const float bv3 = bf3v[co0 + lr];
#pragma unroll
    for (int r = 0; r < 4; ++r) {
        const int row = lk * 4 + r;
        const unsigned short h = f2bf(a3[r] + bv3);
        s_out[row * 264 + co0 + lr] = h;
        const float vq = bf2f(h);
        float np = vq * vq;
        np += __shfl_xor(np, 1);
        np += __shfl_xor(np, 2);
        np += __shfl_xor(np, 4);
        np += __shfl_xor(np, 8);
        if (lr == 0) s_red[row][w] = np;
    }
    __syncthreads();
    if (tid < 16) {
        float s4 = 0.f;
#pragma unroll
        for (int ww = 0; ww < 16; ++ww) s4 += s_red[tid][ww];
        s_fn[tid] = s4;
    }
    __syncthreads();

    // ------------------------- score phase -------------------------
    // wave w < 10 owns N-frag n = w; waves 10..15 contribute -inf/0 to the
    // reductions (and skip the MFMA + store).
    const bool act = (w < 10);
    f32x4 acc = {0.f, 0.f, 0.f, 0.f};
    const unsigned short* __restrict__ Tp = tB + ((size_t)b * TTEXT) * 256;

#pragma unroll
    for (int c = 0; c < 8; ++c) {
        const int d = c * 32 + koff;
        const bf16x8 a = *(const bf16x8*)(s_out + lr * 264 + d);
        if (act) {
            const bf16x8 bb = *(const bf16x8*)(Tp + ((size_t)(w * 16 + lr)) * 256 + d);
            acc = __builtin_amdgcn_mfma_f32_16x16x32_bf16(a, bb, acc, 0, 0, 0);
        }
    }

    float fn[4];
#pragma unroll
    for (int r = 0; r < 4; ++r) fn[r] = s_fn[lk * 4 + r];
    float tn = 0.f; bool mk = true;
    if (act) {
        const int j = w * 16 + lr;
        tn = tnorm[b * TTEXT + j];
        mk = xmask[b * TTEXT + j] != 0;
    }
    float sc[4];
#pragma unroll
    for (int r = 0; r < 4; ++r) {
        const float d2 = fn[r] + tn - 2.0f * acc[r];
        const float sv = -sqrtf(fmaxf(d2, 0.0f));
        sc[r] = mk ? -INFINITY : sv;
    }

    // pass 1: wave-local max per row
#pragma unroll
    for (int r = 0; r < 4; ++r) {
        float mx = sc[r];
        mx = fmaxf(mx, __shfl_xor(mx, 1));
        mx = fmaxf(mx, __shfl_xor(mx, 2));
        mx = fmaxf(mx, __shfl_xor(mx, 4));
        mx = fmaxf(mx, __shfl_xor(mx, 8));
        if (lr == 0) s_red[lk * 4 + r][w] = mx;
    }
    __syncthreads();
    // pass 2: global max + wave-local exp-sum
    float gmax[4];
#pragma unroll
    for (int r = 0; r < 4; ++r) {
        const int row = lk * 4 + r;
        float g = s_red[row][0];
#pragma unroll
        for (int ww = 1; ww < 16; ++ww) g = fmaxf(g, s_red[row][ww]);
        gmax[r] = g;
        float sm = act ? expf(sc[r] - g) : 0.0f;
        sm += __shfl_xor(sm, 1);
        sm += __shfl_xor(sm, 2);
        sm += __shfl_xor(sm, 4);
        sm += __shfl_xor(sm, 8);
        if (lr == 0) s_red2[row][w] = sm;
    }
    __syncthreads();

    const float cst = s_lg[161] - s_lg[961] + s_lg[801];
#pragma unroll
    for (int r = 0; r < 4; ++r) {
        const int row = lk * 4 + r;
        float ssum = s_red2[row][0];
#pragma unroll
        for (int ww = 1; ww < 16; ++ww) ssum += s_red2[row][ww];
        const float lse = gmax[r] + logf(ssum);
        const int grow = t0 + row;
        const float rowterm = cst - s_lg[grow + 1] - s_lg[801 - grow];
        if (act) {
            const int j = w * 16 + lr;
            const float prior = rowterm - s_lg[j + 1] - s_lg[160 - j]
                              + s_lg[grow + j + 1] + s_lg[960 - grow - j];
            out[((size_t)(b * TFEAT + grow)) * TTEXT + j] = sc[r] - lse + prior;
        }
    }
}

extern "C" void kernel_launch(void* const* d_in, const int* in_sizes, int n_in,
                              void* d_out, int out_size, void* d_ws, size_t ws_size,
                              hipStream_t stream) {
    const float* text  = (const float*)d_in[0];
    const float* feats = (const float*)d_in[1];
    const unsigned char* xmask = (const unsigned char*)d_in[4];
    const float* t_w1 = (const float*)d_in[5];
    const float* t_b1 = (const float*)d_in[6];
    const float* t_w2 = (const float*)d_in[7];
    const float* t_b2 = (const float*)d_in[8];
    const float* f_w1 = (const float*)d_in[9];
    const float* f_b1 = (const float*)d_in[10];
    const float* f_w2 = (const float*)d_in[11];
    const float* f_b2 = (const float*)d_in[12];
    const float* f_w3 = (const float*)d_in[13];
    const float* f_b3 = (const float*)d_in[14];
    float* out = (float*)d_out;

    char* wp = (char*)d_ws;
    auto alloc = [&](size_t bytes) -> void* {
        void* p = wp; wp += (bytes + 255) & ~(size_t)255; return p;
    };
    unsigned short* wb_f1 = (unsigned short*)alloc(73728 * 2);
    unsigned short* wb_f2 = (unsigned short*)alloc(196608 * 2);
    unsigned short* wb_f3 = (unsigned short*)alloc(65536 * 2);
    unsigned short* tB = (unsigned short*)alloc((size_t)NB * TTEXT * 256 * 2);
    float* tnorm = (float*)alloc((size_t)NB * TTEXT * 4);

    // K1: text stem (inline f32 weights) + feats-weight transform
    k1_text_prep<<<368, 1024, 0, stream>>>(
        text, t_w1, t_b1, t_w2, t_b2, f_w1, f_w2, f_w3,
        wb_f1, wb_f2, wb_f3, tB, tnorm);

    // K2: feats stem + fused score
    k2_feats_score<<<200, 1024, 0, stream>>>(
        feats, xmask, wb_f1, f_b1, wb_f2, f_b2, wb_f3, f_b3,
        tB, tnorm, out);
}

// Round 11
// 38.093 us; speedup vs baseline: 3.0857x; 3.0857x over previous
//
#include <hip/hip_runtime.h>
#include <math.h>

#define NB 4
#define TTEXT 160
#define TFEAT 800

// replica layout (elements): [wt1 | wt2 | wf1 | wf2 | wf3]
#define OFF_T1 0
#define OFF_T2 196608
#define OFF_F1 262144
#define OFF_F2 335872
#define OFF_F3 532480
#define REP_ELEMS 598016

typedef __bf16 bf16x8 __attribute__((ext_vector_type(8)));
typedef float f32x4 __attribute__((ext_vector_type(4)));

__device__ inline unsigned short f2bf(float f) {
    unsigned int u = __builtin_bit_cast(unsigned int, f);
    unsigned int r = u + 0x7fffu + ((u >> 16) & 1u);
    return (unsigned short)(r >> 16);
}
__device__ inline float bf2f(unsigned short h) {
    unsigned int u = ((unsigned int)h) << 16;
    return __builtin_bit_cast(float, u);
}

// f32 lgamma for integer arguments n>=1 (Stirling, n<8 promoted by 8).
__device__ inline float lgamma_int(float nf) {
    float z = nf, corr = 0.0f;
    if (nf < 8.0f) {
        const float p = nf * (nf + 1.0f) * (nf + 2.0f) * (nf + 3.0f)
                      * (nf + 4.0f) * (nf + 5.0f) * (nf + 6.0f) * (nf + 7.0f);
        z = nf + 8.0f;
        corr = logf(p);
    }
    const float lz = logf(z);
    const float iz = 1.0f / z;
    const float s = (z - 0.5f) * lz - z + 0.918938533f
                  + iz * (0.0833333333f - iz * iz * 0.00277777778f);
    return s - corr;
}

// XCD id of the executing CU (verified on MI355X: HW_REG_XCC_ID = hwreg 20).
// simm16 = id(20) | offset(0)<<6 | (width-1=31)<<11 = 63508.
__device__ inline unsigned xcd_id() {
    return __builtin_amdgcn_s_getreg(63508) & 7u;
}

// ---------------------------------------------------------------------------
// Prep: weight transform into B-fragment-native layout, REPLICATED x8.
// Grid = 2336*8 blocks; block bid handles element set (bid>>3) for replica
// (bid&7). Under the default round-robin block->XCD mapping, replica r is
// written entirely by CUs on XCD r, leaving it resident in that XCD's L2.
// Replicas are identical, so consumers are correct under ANY mapping.
// ---------------------------------------------------------------------------
__global__ __launch_bounds__(256) void prep_kernel(
    const float* __restrict__ tw1, const float* __restrict__ tw2,
    const float* __restrict__ fw1, const float* __restrict__ fw2,
    const float* __restrict__ fw3,
    unsigned short* __restrict__ wb_all)
{
    const int rep = blockIdx.x & 7;
    const int u = (blockIdx.x >> 3) * 256 + threadIdx.x;
    int rem = u;
    int CIN, CINP, K; const float* src; int off;
    if (rem < 196608)                  { CIN = 256; CINP = 256; K = 3; src = tw1; off = OFF_T1; }
    else if ((rem -= 196608) < 65536)  { CIN = 256; CINP = 256; K = 1; src = tw2; off = OFF_T2; }
    else if ((rem -= 65536) < 73728)   { CIN = 80;  CINP = 96;  K = 3; src = fw1; off = OFF_F1; }
    else if ((rem -= 73728) < 196608)  { CIN = 256; CINP = 256; K = 3; src = fw2; off = OFF_F2; }
    else { rem -= 196608;                CIN = 256; CINP = 256; K = 1; src = fw3; off = OFF_F3; }
    const int q = rem & 31, coc = rem >> 5, co = coc & 255, c = coc >> 8;
    const int cpk = CINP / 32, k = c / cpk, ci = (c % cpk) * 32 + q;
    const float v = (ci < CIN) ? src[((size_t)co * CIN + ci) * K + k] : 0.0f;
    wb_all[(size_t)rep * REP_ELEMS + off + rem] = f2bf(v);
}

// ---------------------------------------------------------------------------
// Fused stems, 1024 threads = 16 waves; wave w owns 16 output channels.
// Identical math to verified round-9 code; the ONLY change is that weight
// pointers select the XCD-local replica.
// ---------------------------------------------------------------------------
__global__ __launch_bounds__(1024) void stems_kernel(
    const float* __restrict__ text, const float* __restrict__ feats,
    const unsigned short* __restrict__ wb_all,
    const float* __restrict__ bt1, const float* __restrict__ bt2,
    const float* __restrict__ bf1v, const float* __restrict__ bf2v,
    const float* __restrict__ bf3v,
    unsigned short* __restrict__ tB, float* __restrict__ tnorm,
    unsigned short* __restrict__ fC, float* __restrict__ fnorm)
{
    __shared__ __align__(16) unsigned short s[11056];
    __shared__ float s_red[16][16];
    const int tid = threadIdx.x;
    const int w  = tid >> 6;        // 0..15
    const int l  = tid & 63;
    const int lr = l & 15;
    const int lk = l >> 4;
    const int co0 = w * 16;         // 16 channels per wave
    const int koff = lk * 8;
    const int bid = blockIdx.x;

    const unsigned short* __restrict__ wbase = wb_all + (size_t)xcd_id() * REP_ELEMS;
    const unsigned short* __restrict__ wt1 = wbase + OFF_T1;
    const unsigned short* __restrict__ wt2 = wbase + OFF_T2;
    const unsigned short* __restrict__ wf1 = wbase + OFF_F1;
    const unsigned short* __restrict__ wf2 = wbase + OFF_F2;
    const unsigned short* __restrict__ wf3 = wbase + OFF_F3;

    if (bid < 40) {
        // ------------------------- text stem -------------------------
        const int b  = bid & 3;
        const int t0 = (bid >> 2) << 4;
        unsigned short* s_in  = s;          // [18][264]
        unsigned short* s_mid = s + 4752;   // [16][264]

        for (int idx = tid; idx < 18 * 64; idx += 1024) {
            const int r = idx >> 6, c4 = idx & 63;
            const int x = t0 - 1 + r;
            float4 v = {0.f, 0.f, 0.f, 0.f};
            if (x >= 0 && x < TTEXT)
                v = *(const float4*)(text + ((size_t)(b * TTEXT + x)) * 256 + c4 * 4);
            unsigned short* p = s_in + r * 264 + c4 * 4;
            p[0] = f2bf(v.x); p[1] = f2bf(v.y); p[2] = f2bf(v.z); p[3] = f2bf(v.w);
        }
        __syncthreads();

        // t1: K=3, CIN=256 -> 24 chunks
        f32x4 acc = {0.f, 0.f, 0.f, 0.f};
#pragma unroll 8
        for (int c = 0; c < 24; ++c) {
            const int k  = c >> 3;
            const int ci = ((c & 7) << 5) + koff;
            const bf16x8 a = *(const bf16x8*)(s_in + (lr + k) * 264 + ci);
            const bf16x8 bb = *(const bf16x8*)(wt1 + (((size_t)c * 256 + co0 + lr) << 5) + koff);
            acc = __builtin_amdgcn_mfma_f32_16x16x32_bf16(a, bb, acc, 0, 0, 0);
        }
        {
            const float bv = bt1[co0 + lr];
#pragma unroll
            for (int r = 0; r < 4; ++r)
                s_mid[(lk * 4 + r) * 264 + co0 + lr] = f2bf(fmaxf(acc[r] + bv, 0.f));
        }
        __syncthreads();

        // t2: K=1 -> 8 chunks, epilogue to global + norm
        f32x4 a2 = {0.f, 0.f, 0.f, 0.f};
#pragma unroll
        for (int c = 0; c < 8; ++c) {
            const bf16x8 a = *(const bf16x8*)(s_mid + lr * 264 + (c << 5) + koff);
            const bf16x8 bb = *(const bf16x8*)(wt2 + (((size_t)c * 256 + co0 + lr) << 5) + koff);
            a2 = __builtin_amdgcn_mfma_f32_16x16x32_bf16(a, bb, a2, 0, 0, 0);
        }
        const float bv2 = bt2[co0 + lr];
#pragma unroll
        for (int r = 0; r < 4; ++r) {
            const int row = lk * 4 + r;
            const unsigned short h = f2bf(a2[r] + bv2);
            tB[((size_t)(b * TTEXT + t0 + row)) * 256 + co0 + lr] = h;
            const float vq = bf2f(h);
            float np = vq * vq;
            np += __shfl_xor(np, 1);
            np += __shfl_xor(np, 2);
            np += __shfl_xor(np, 4);
            np += __shfl_xor(np, 8);
            if (lr == 0) s_red[row][w] = np;
        }
        __syncthreads();
        if (tid < 16) {
            float s4 = 0.f;
#pragma unroll
            for (int ww = 0; ww < 16; ++ww) s4 += s_red[tid][ww];
            tnorm[b * TTEXT + t0 + tid] = s4;
        }
    } else {
        // ------------------------- feats stem -------------------------
        const int fb = bid - 40;
        const int b  = fb & 3;
        const int t0 = (fb >> 2) << 4;
        unsigned short* s_fin = s;          // [20][104]
        unsigned short* s_b1  = s + 2080;   // [18][264]
        unsigned short* s_b2  = s + 6832;   // [16][264]

        for (int idx = tid; idx < 20 * 24; idx += 1024) {
            const int r  = idx / 24, c4 = idx - r * 24;
            const int ch = c4 * 4;
            const int x  = t0 - 2 + r;
            float4 v = {0.f, 0.f, 0.f, 0.f};
            if (ch < 80 && x >= 0 && x < TFEAT)
                v = *(const float4*)(feats + ((size_t)(b * TFEAT + x)) * 80 + ch);
            unsigned short* p = s_fin + r * 104 + ch;
            p[0] = f2bf(v.x); p[1] = f2bf(v.y); p[2] = f2bf(v.z); p[3] = f2bf(v.w);
        }
        __syncthreads();

        // f1: K=3, CINP=96 -> 9 chunks; 18 output rows (2 M-frags, masked)
        f32x4 acc1[2];
#pragma unroll
        for (int m = 0; m < 2; ++m) acc1[m] = {0.f, 0.f, 0.f, 0.f};
#pragma unroll
        for (int c = 0; c < 9; ++c) {
            const int k  = c / 3;
            const int ci = (c - k * 3) * 32 + koff;
            const bf16x8 bb = *(const bf16x8*)(wf1 + (((size_t)c * 256 + co0 + lr) << 5) + koff);
#pragma unroll
            for (int m = 0; m < 2; ++m) {
                int rr = m * 16 + lr + k;
                if (rr > 19) rr = 19;   // clamp; rows >=18 masked at write
                const bf16x8 a = *(const bf16x8*)(s_fin + rr * 104 + ci);
                acc1[m] = __builtin_amdgcn_mfma_f32_16x16x32_bf16(a, bb, acc1[m], 0, 0, 0);
            }
        }
        {
            const float bv = bf1v[co0 + lr];
#pragma unroll
            for (int m = 0; m < 2; ++m)
#pragma unroll
                for (int r = 0; r < 4; ++r) {
                    const int i = m * 16 + lk * 4 + r;
                    if (i < 18)
                        s_b1[i * 264 + co0 + lr] = f2bf(fmaxf(acc1[m][r] + bv, 0.f));
                }
        }
        __syncthreads();

        // f2: K=3, CIN=256 -> 24 chunks
        f32x4 acc2 = {0.f, 0.f, 0.f, 0.f};
#pragma unroll 8
        for (int c = 0; c < 24; ++c) {
            const int k  = c >> 3;
            const int ci = ((c & 7) << 5) + koff;
            const bf16x8 a = *(const bf16x8*)(s_b1 + (lr + k) * 264 + ci);
            const bf16x8 bb = *(const bf16x8*)(wf2 + (((size_t)c * 256 + co0 + lr) << 5) + koff);
            acc2 = __builtin_amdgcn_mfma_f32_16x16x32_bf16(a, bb, acc2, 0, 0, 0);
        }
        {
            const float bv = bf2v[co0 + lr];
#pragma unroll
            for (int r = 0; r < 4; ++r)
                s_b2[(lk * 4 + r) * 264 + co0 + lr] = f2bf(fmaxf(acc2[r] + bv, 0.f));
        }
        __syncthreads();

        // f3: K=1 -> 8 chunks, epilogue to global + norm
        f32x4 a3 = {0.f, 0.f, 0.f, 0.f};
#pragma unroll
        for (int c = 0; c < 8; ++c) {
            const bf16x8 a = *(const bf16x8*)(s_b2 + lr * 264 + (c << 5) + koff);
            const bf16x8 bb = *(const bf16x8*)(wf3 + (((size_t)c * 256 + co0 + lr) << 5) + koff);
            a3 = __builtin_amdgcn_mfma_f32_16x16x32_bf16(a, bb, a3, 0, 0, 0);
        }
        const float bv3 = bf3v[co0 + lr];
#pragma unroll
        for (int r = 0; r < 4; ++r) {
            const int row = lk * 4 + r;
            const unsigned short h = f2bf(a3[r] + bv3);
            fC[((size_t)(b * TFEAT + t0 + row)) * 256 + co0 + lr] = h;
            const float vq = bf2f(h);
            float np = vq * vq;
            np += __shfl_xor(np, 1);
            np += __shfl_xor(np, 2);
            np += __shfl_xor(np, 4);
            np += __shfl_xor(np, 8);
            if (lr == 0) s_red[row][w] = np;
        }
        __syncthreads();
        if (tid < 16) {
            float s4 = 0.f;
#pragma unroll
            for (int ww = 0; ww < 16; ++ww) s4 += s_red[tid][ww];
            fnorm[b * TFEAT + t0 + tid] = s4;
        }
    }
}

// ---------------------------------------------------------------------------
// Score: 512 threads / 8 waves per block; wave w handles N-frags {w} and
// (w<2 ? {w+8} : none). LDS Stirling-lgamma table; 2-barrier LDS softmax.
// Verified round-9 code, unchanged.
// ---------------------------------------------------------------------------
__global__ __launch_bounds__(512) void score_mfma(
    const unsigned short* __restrict__ F, const unsigned short* __restrict__ Tt,
    const float* __restrict__ fnorm, const float* __restrict__ tnorm,
    const unsigned char* __restrict__ xmask,
    float* __restrict__ out)
{
    const int b  = blockIdx.y;
    const int tid = threadIdx.x;
    const int w  = tid >> 6;        // 0..7
    const int l  = tid & 63;
    const int lr = l & 15;
    const int lk = l >> 4;
    const int i0 = blockIdx.x * 16;
    const int NI = (w < 2) ? 2 : 1;

    __shared__ float s_lg[962];
    __shared__ float s_red[16][8];
    __shared__ float s_red2[16][8];

    for (int idx = tid; idx < 962; idx += 512)
        s_lg[idx] = (idx >= 1) ? lgamma_int((float)idx) : 0.0f;

    f32x4 acc[2];
#pragma unroll
    for (int ni = 0; ni < 2; ++ni) acc[ni] = {0.f, 0.f, 0.f, 0.f};

    const unsigned short* __restrict__ Fp = F + ((size_t)(b * TFEAT + i0 + lr)) * 256;
    const unsigned short* __restrict__ Tp = Tt + ((size_t)b * TTEXT) * 256;

#pragma unroll
    for (int c = 0; c < 8; ++c) {
        const int d = c * 32 + lk * 8;
        const bf16x8 a = *(const bf16x8*)(Fp + d);
#pragma unroll
        for (int ni = 0; ni < 2; ++ni) {
            if (ni < NI) {
                const int n = w + ni * 8;
                const bf16x8 bb = *(const bf16x8*)(Tp + ((size_t)(n * 16 + lr)) * 256 + d);
                acc[ni] = __builtin_amdgcn_mfma_f32_16x16x32_bf16(a, bb, acc[ni], 0, 0, 0);
            }
        }
    }

    float fn[4];
#pragma unroll
    for (int r = 0; r < 4; ++r) fn[r] = fnorm[b * TFEAT + i0 + lk * 4 + r];
    float tn[2]; bool mk[2];
#pragma unroll
    for (int ni = 0; ni < 2; ++ni) {
        if (ni < NI) {
            const int j = (w + ni * 8) * 16 + lr;
            tn[ni] = tnorm[b * TTEXT + j];
            mk[ni] = xmask[b * TTEXT + j] != 0;
        } else { tn[ni] = 0.f; mk[ni] = true; }
    }
    float sc[2][4];
#pragma unroll
    for (int ni = 0; ni < 2; ++ni)
#pragma unroll
        for (int r = 0; r < 4; ++r) {
            const float d2 = fn[r] + tn[ni] - 2.0f * acc[ni][r];
            const float sv = -sqrtf(fmaxf(d2, 0.0f));
            sc[ni][r] = mk[ni] ? -INFINITY : sv;
        }

    // pass 1: wave-local max per row
#pragma unroll
    for (int r = 0; r < 4; ++r) {
        float mx = fmaxf(sc[0][r], sc[1][r]);
        mx = fmaxf(mx, __shfl_xor(mx, 1));
        mx = fmaxf(mx, __shfl_xor(mx, 2));
        mx = fmaxf(mx, __shfl_xor(mx, 4));
        mx = fmaxf(mx, __shfl_xor(mx, 8));
        if (lr == 0) s_red[lk * 4 + r][w] = mx;
    }
    __syncthreads();
    // pass 2: global max + wave-local exp-sum
    float gmax[4];
#pragma unroll
    for (int r = 0; r < 4; ++r) {
        const int row = lk * 4 + r;
        float g = s_red[row][0];
#pragma unroll
        for (int ww = 1; ww < 8; ++ww) g = fmaxf(g, s_red[row][ww]);
        gmax[r] = g;
        float sm = 0.f;
#pragma unroll
        for (int ni = 0; ni < 2; ++ni)
            if (ni < NI) sm += expf(sc[ni][r] - g);
        sm += __shfl_xor(sm, 1);
        sm += __shfl_xor(sm, 2);
        sm += __shfl_xor(sm, 4);
        sm += __shfl_xor(sm, 8);
        if (lr == 0) s_red2[row][w] = sm;
    }
    __syncthreads();

    const float cst = s_lg[161] - s_lg[961] + s_lg[801];
#pragma unroll
    for (int r = 0; r < 4; ++r) {
        const int row = lk * 4 + r;
        float ssum = s_red2[row][0];
#pragma unroll
        for (int ww = 1; ww < 8; ++ww) ssum += s_red2[row][ww];
        const float lse = gmax[r] + logf(ssum);
        const int grow = i0 + row;
        const float rowterm = cst - s_lg[grow + 1] - s_lg[801 - grow];
#pragma unroll
        for (int ni = 0; ni < 2; ++ni) {
            if (ni < NI) {
                const int j = (w + ni * 8) * 16 + lr;
                const float prior = rowterm - s_lg[j + 1] - s_lg[160 - j]
                                  + s_lg[grow + j + 1] + s_lg[960 - grow - j];
                out[((size_t)(b * TFEAT + grow)) * TTEXT + j] = sc[ni][r] - lse + prior;
            }
        }
    }
}

extern "C" void kernel_launch(void* const* d_in, const int* in_sizes, int n_in,
                              void* d_out, int out_size, void* d_ws, size_t ws_size,
                              hipStream_t stream) {
    const float* text  = (const float*)d_in[0];
    const float* feats = (const float*)d_in[1];
    const unsigned char* xmask = (const unsigned char*)d_in[4];
    const float* t_w1 = (const float*)d_in[5];
    const float* t_b1 = (const float*)d_in[6];
    const float* t_w2 = (const float*)d_in[7];
    const float* t_b2 = (const float*)d_in[8];
    const float* f_w1 = (const float*)d_in[9];
    const float* f_b1 = (const float*)d_in[10];
    const float* f_w2 = (const float*)d_in[11];
    const float* f_b2 = (const float*)d_in[12];
    const float* f_w3 = (const float*)d_in[13];
    const float* f_b3 = (const float*)d_in[14];
    float* out = (float*)d_out;

    char* wp = (char*)d_ws;
    auto alloc = [&](size_t bytes) -> void* {
        void* p = wp; wp += (bytes + 255) & ~(size_t)255; return p;
    };
    unsigned short* wb_all = (unsigned short*)alloc((size_t)8 * REP_ELEMS * 2);
    unsigned short* tB = (unsigned short*)alloc((size_t)NB * TTEXT * 256 * 2);
    unsigned short* fC = (unsigned short*)alloc((size_t)NB * TFEAT * 256 * 2);
    float* fnorm = (float*)alloc((size_t)NB * TFEAT * 4);
    float* tnorm = (float*)alloc((size_t)NB * TTEXT * 4);

    // 8 replicas, one per XCD (block bid -> replica bid&7; HW round-robins
    // blocks across XCDs, so replica r is written by XCD r's L2).
    prep_kernel<<<2336 * 8, 256, 0, stream>>>(
        t_w1, t_w2, f_w1, f_w2, f_w3, wb_all);

    stems_kernel<<<240, 1024, 0, stream>>>(
        text, feats, wb_all,
        t_b1, t_b2, f_b1, f_b2, f_b3,
        tB, tnorm, fC, fnorm);

    score_mfma<<<dim3(50, NB), 512, 0, stream>>>(fC, tB, fnorm, tnorm, xmask, out);
}

// Round 12
// 31.984 us; speedup vs baseline: 3.6750x; 1.1910x over previous
//
#include <hip/hip_runtime.h>
#include <math.h>

#define NB 4
#define TTEXT 160
#define TFEAT 800

typedef __bf16 bf16x8 __attribute__((ext_vector_type(8)));
typedef float f32x4 __attribute__((ext_vector_type(4)));

__device__ inline unsigned short f2bf(float f) {
    unsigned int u = __builtin_bit_cast(unsigned int, f);
    unsigned int r = u + 0x7fffu + ((u >> 16) & 1u);
    return (unsigned short)(r >> 16);
}
__device__ inline float bf2f(unsigned short h) {
    unsigned int u = ((unsigned int)h) << 16;
    return __builtin_bit_cast(float, u);
}

// f32 lgamma for integer arguments n>=1 (Stirling, n<8 promoted by 8).
__device__ inline float lgamma_int(float nf) {
    float z = nf, corr = 0.0f;
    if (nf < 8.0f) {
        const float p = nf * (nf + 1.0f) * (nf + 2.0f) * (nf + 3.0f)
                      * (nf + 4.0f) * (nf + 5.0f) * (nf + 6.0f) * (nf + 7.0f);
        z = nf + 8.0f;
        corr = logf(p);
    }
    const float lz = logf(z);
    const float iz = 1.0f / z;
    const float s = (z - 0.5f) * lz - z + 0.918938533f
                  + iz * (0.0833333333f - iz * iz * 0.00277777778f);
    return s - corr;
}

// async global->LDS, 16B per lane; LDS dest must be wave-uniform base.
__device__ __forceinline__ void gll16(const unsigned short* g, unsigned short* l) {
    __builtin_amdgcn_global_load_lds(
        (const __attribute__((address_space(1))) void*)g,
        (__attribute__((address_space(3))) void*)l, 16, 0, 0);
}
__device__ __forceinline__ unsigned short* bufsel(
    unsigned short* a, unsigned short* b, unsigned short* c_, int i) {
    return (i == 0) ? a : (i == 1) ? b : c_;
}

// wave w stages its 512-elem (1KB) slice of 16KB chunk c into buf.
#define STAGE(W, c, buf) gll16((W) + ((size_t)(c) << 13) + (w << 9) + (l << 3), (buf) + (w << 9))
#define WAITV(n) asm volatile("s_waitcnt vmcnt(" #n ")" ::: "memory")

// ---------------------------------------------------------------------------
// Prep: flat exact grid (2336 blocks x 256). Weight transform into
// B-fragment-native layout Wb[c][co][q]. Round-9 verified, unchanged.
// ---------------------------------------------------------------------------
__global__ __launch_bounds__(256) void prep_kernel(
    const float* __restrict__ tw1, const float* __restrict__ tw2,
    const float* __restrict__ fw1, const float* __restrict__ fw2,
    const float* __restrict__ fw3,
    unsigned short* __restrict__ wb_t1, unsigned short* __restrict__ wb_t2,
    unsigned short* __restrict__ wb_f1, unsigned short* __restrict__ wb_f2,
    unsigned short* __restrict__ wb_f3)
{
    const int u = blockIdx.x * 256 + threadIdx.x;
    int rem = u;
    int CIN, CINP, K; const float* src; unsigned short* dst;
    if (rem < 196608)                  { CIN = 256; CINP = 256; K = 3; src = tw1; dst = wb_t1; }
    else if ((rem -= 196608) < 65536)  { CIN = 256; CINP = 256; K = 1; src = tw2; dst = wb_t2; }
    else if ((rem -= 65536) < 73728)   { CIN = 80;  CINP = 96;  K = 3; src = fw1; dst = wb_f1; }
    else if ((rem -= 73728) < 196608)  { CIN = 256; CINP = 256; K = 3; src = fw2; dst = wb_f2; }
    else { rem -= 196608;                CIN = 256; CINP = 256; K = 1; src = fw3; dst = wb_f3; }
    const int q = rem & 31, coc = rem >> 5, co = coc & 255, c = coc >> 8;
    const int cpk = CINP / 32, k = c / cpk, ci = (c % cpk) * 32 + q;
    const float v = (ci < CIN) ? src[((size_t)co * CIN + ci) * K + k] : 0.0f;
    dst[rem] = f2bf(v);
}

// ---------------------------------------------------------------------------
// Fused stems, 1024 threads = 16 waves; wave w owns 16 output channels.
// Round-9 math unchanged; weights now STREAMED into LDS via
// global_load_lds (16B/lane), triple-buffered, depth-2 prefetch with
// counted vmcnt — converts per-wave scattered-latency loads into the
// m97-style pipeline. Each wave reads back only its own 1KB slice
// (conflict-free ds_read_b128, no barriers in the chunk loops).
// ---------------------------------------------------------------------------
__global__ __launch_bounds__(1024) void stems_kernel(
    const float* __restrict__ text, const float* __restrict__ feats,
    const unsigned short* __restrict__ wt1, const float* __restrict__ bt1,
    const unsigned short* __restrict__ wt2, const float* __restrict__ bt2,
    const unsigned short* __restrict__ wf1, const float* __restrict__ bf1v,
    const unsigned short* __restrict__ wf2, const float* __restrict__ bf2v,
    const unsigned short* __restrict__ wf3, const float* __restrict__ bf3v,
    unsigned short* __restrict__ tB, float* __restrict__ tnorm,
    unsigned short* __restrict__ fC, float* __restrict__ fnorm)
{
    __shared__ __align__(16) unsigned short s[11056];
    __shared__ __align__(16) unsigned short ws0[8192];
    __shared__ __align__(16) unsigned short ws1[8192];
    __shared__ __align__(16) unsigned short ws2[8192];
    __shared__ float s_red[16][16];
    const int tid = threadIdx.x;
    const int w  = tid >> 6;        // 0..15
    const int l  = tid & 63;
    const int lr = l & 15;
    const int lk = l >> 4;
    const int co0 = w * 16;         // 16 channels per wave
    const int koff = lk * 8;
    const int bid = blockIdx.x;

    if (bid < 40) {
        // ------------------------- text stem -------------------------
        const int b  = bid & 3;
        const int t0 = (bid >> 2) << 4;
        unsigned short* s_in  = s;          // [18][264]
        unsigned short* s_mid = s + 4752;   // [16][264]

        for (int idx = tid; idx < 18 * 64; idx += 1024) {
            const int r = idx >> 6, c4 = idx & 63;
            const int x = t0 - 1 + r;
            float4 v = {0.f, 0.f, 0.f, 0.f};
            if (x >= 0 && x < TTEXT)
                v = *(const float4*)(text + ((size_t)(b * TTEXT + x)) * 256 + c4 * 4);
            unsigned short* p = s_in + r * 264 + c4 * 4;
            p[0] = f2bf(v.x); p[1] = f2bf(v.y); p[2] = f2bf(v.z); p[3] = f2bf(v.w);
        }
        __syncthreads();

        // t1: K=3, CIN=256 -> 24 chunks (staged weights)
        f32x4 acc = {0.f, 0.f, 0.f, 0.f};
        STAGE(wt1, 0, ws0);
        STAGE(wt1, 1, ws1);
#pragma unroll 3
        for (int c = 0; c < 24; ++c) {
            unsigned short* cur = bufsel(ws0, ws1, ws2, c % 3);
            if (c < 22) {
                unsigned short* nxt = bufsel(ws0, ws1, ws2, (c + 2) % 3);
                STAGE(wt1, c + 2, nxt);
                WAITV(2);
            } else if (c == 22) { WAITV(1); } else { WAITV(0); }
            const int k  = c >> 3;
            const int ci = ((c & 7) << 5) + koff;
            const bf16x8 a = *(const bf16x8*)(s_in + (lr + k) * 264 + ci);
            const bf16x8 bb = *(const bf16x8*)(cur + (w << 9) + lr * 32 + lk * 8);
            acc = __builtin_amdgcn_mfma_f32_16x16x32_bf16(a, bb, acc, 0, 0, 0);
        }
        {
            const float bv = bt1[co0 + lr];
#pragma unroll
            for (int r = 0; r < 4; ++r)
                s_mid[(lk * 4 + r) * 264 + co0 + lr] = f2bf(fmaxf(acc[r] + bv, 0.f));
        }
        __syncthreads();

        // t2: K=1 -> 8 chunks (staged weights)
        f32x4 a2 = {0.f, 0.f, 0.f, 0.f};
        STAGE(wt2, 0, ws0);
        STAGE(wt2, 1, ws1);
#pragma unroll
        for (int c = 0; c < 8; ++c) {
            unsigned short* cur = bufsel(ws0, ws1, ws2, c % 3);
            if (c < 6) {
                unsigned short* nxt = bufsel(ws0, ws1, ws2, (c + 2) % 3);
                STAGE(wt2, c + 2, nxt);
                WAITV(2);
            } else if (c == 6) { WAITV(1); } else { WAITV(0); }
            const bf16x8 a = *(const bf16x8*)(s_mid + lr * 264 + (c << 5) + koff);
            const bf16x8 bb = *(const bf16x8*)(cur + (w << 9) + lr * 32 + lk * 8);
            a2 = __builtin_amdgcn_mfma_f32_16x16x32_bf16(a, bb, a2, 0, 0, 0);
        }
        const float bv2 = bt2[co0 + lr];
#pragma unroll
        for (int r = 0; r < 4; ++r) {
            const int row = lk * 4 + r;
            const unsigned short h = f2bf(a2[r] + bv2);
            tB[((size_t)(b * TTEXT + t0 + row)) * 256 + co0 + lr] = h;
            const float vq = bf2f(h);
            float np = vq * vq;
            np += __shfl_xor(np, 1);
            np += __shfl_xor(np, 2);
            np += __shfl_xor(np, 4);
            np += __shfl_xor(np, 8);
            if (lr == 0) s_red[row][w] = np;
        }
        __syncthreads();
        if (tid < 16) {
            float s4 = 0.f;
#pragma unroll
            for (int ww = 0; ww < 16; ++ww) s4 += s_red[tid][ww];
            tnorm[b * TTEXT + t0 + tid] = s4;
        }
    } else {
        // ------------------------- feats stem -------------------------
        const int fb = bid - 40;
        const int b  = fb & 3;
        const int t0 = (fb >> 2) << 4;
        unsigned short* s_fin = s;          // [20][104]
        unsigned short* s_b1  = s + 2080;   // [18][264]
        unsigned short* s_b2  = s + 6832;   // [16][264]

        for (int idx = tid; idx < 20 * 24; idx += 1024) {
            const int r  = idx / 24, c4 = idx - r * 24;
            const int ch = c4 * 4;
            const int x  = t0 - 2 + r;
            float4 v = {0.f, 0.f, 0.f, 0.f};
            if (ch < 80 && x >= 0 && x < TFEAT)
                v = *(const float4*)(feats + ((size_t)(b * TFEAT + x)) * 80 + ch);
            unsigned short* p = s_fin + r * 104 + ch;
            p[0] = f2bf(v.x); p[1] = f2bf(v.y); p[2] = f2bf(v.z); p[3] = f2bf(v.w);
        }
        __syncthreads();

        // f1: K=3, CINP=96 -> 9 chunks (staged); 18 output rows (2 M-frags)
        f32x4 acc1[2];
#pragma unroll
        for (int m = 0; m < 2; ++m) acc1[m] = {0.f, 0.f, 0.f, 0.f};
        STAGE(wf1, 0, ws0);
        STAGE(wf1, 1, ws1);
#pragma unroll
        for (int c = 0; c < 9; ++c) {
            unsigned short* cur = bufsel(ws0, ws1, ws2, c % 3);
            if (c < 7) {
                unsigned short* nxt = bufsel(ws0, ws1, ws2, (c + 2) % 3);
                STAGE(wf1, c + 2, nxt);
                WAITV(2);
            } else if (c == 7) { WAITV(1); } else { WAITV(0); }
            const int k  = c / 3;
            const int ci = (c - k * 3) * 32 + koff;
            const bf16x8 bb = *(const bf16x8*)(cur + (w << 9) + lr * 32 + lk * 8);
#pragma unroll
            for (int m = 0; m < 2; ++m) {
                int rr = m * 16 + lr + k;
                if (rr > 19) rr = 19;   // clamp; rows >=18 masked at write
                const bf16x8 a = *(const bf16x8*)(s_fin + rr * 104 + ci);
                acc1[m] = __builtin_amdgcn_mfma_f32_16x16x32_bf16(a, bb, acc1[m], 0, 0, 0);
            }
        }
        {
            const float bv = bf1v[co0 + lr];
#pragma unroll
            for (int m = 0; m < 2; ++m)
#pragma unroll
                for (int r = 0; r < 4; ++r) {
                    const int i = m * 16 + lk * 4 + r;
                    if (i < 18)
                        s_b1[i * 264 + co0 + lr] = f2bf(fmaxf(acc1[m][r] + bv, 0.f));
                }
        }
        __syncthreads();

        // f2: K=3, CIN=256 -> 24 chunks (staged)
        f32x4 acc2 = {0.f, 0.f, 0.f, 0.f};
        STAGE(wf2, 0, ws0);
        STAGE(wf2, 1, ws1);
#pragma unroll 3
        for (int c = 0; c < 24; ++c) {
            unsigned short* cur = bufsel(ws0, ws1, ws2, c % 3);
            if (c < 22) {
                unsigned short* nxt = bufsel(ws0, ws1, ws2, (c + 2) % 3);
                STAGE(wf2, c + 2, nxt);
                WAITV(2);
            } else if (c == 22) { WAITV(1); } else { WAITV(0); }
            const int k  = c >> 3;
            const int ci = ((c & 7) << 5) + koff;
            const bf16x8 a = *(const bf16x8*)(s_b1 + (lr + k) * 264 + ci);
            const bf16x8 bb = *(const bf16x8*)(cur + (w << 9) + lr * 32 + lk * 8);
            acc2 = __builtin_amdgcn_mfma_f32_16x16x32_bf16(a, bb, acc2, 0, 0, 0);
        }
        {
            const float bv = bf2v[co0 + lr];
#pragma unroll
            for (int r = 0; r < 4; ++r)
                s_b2[(lk * 4 + r) * 264 + co0 + lr] = f2bf(fmaxf(acc2[r] + bv, 0.f));
        }
        __syncthreads();

        // f3: K=1 -> 8 chunks (staged), epilogue to global + norm
        f32x4 a3 = {0.f, 0.f, 0.f, 0.f};
        STAGE(wf3, 0, ws0);
        STAGE(wf3, 1, ws1);
#pragma unroll
        for (int c = 0; c < 8; ++c) {
            unsigned short* cur = bufsel(ws0, ws1, ws2, c % 3);
            if (c < 6) {
                unsigned short* nxt = bufsel(ws0, ws1, ws2, (c + 2) % 3);
                STAGE(wf3, c + 2, nxt);
                WAITV(2);
            } else if (c == 6) { WAITV(1); } else { WAITV(0); }
            const bf16x8 a = *(const bf16x8*)(s_b2 + lr * 264 + (c << 5) + koff);
            const bf16x8 bb = *(const bf16x8*)(cur + (w << 9) + lr * 32 + lk * 8);
            a3 = __builtin_amdgcn_mfma_f32_16x16x32_bf16(a, bb, a3, 0, 0, 0);
        }
        const float bv3 = bf3v[co0 + lr];
#pragma unroll
        for (int r = 0; r < 4; ++r) {
            const int row = lk * 4 + r;
            const unsigned short h = f2bf(a3[r] + bv3);
            fC[((size_t)(b * TFEAT + t0 + row)) * 256 + co0 + lr] = h;
            const float vq = bf2f(h);
            float np = vq * vq;
            np += __shfl_xor(np, 1);
            np += __shfl_xor(np, 2);
            np += __shfl_xor(np, 4);
            np += __shfl_xor(np, 8);
            if (lr == 0) s_red[row][w] = np;
        }
        __syncthreads();
        if (tid < 16) {
            float s4 = 0.f;
#pragma unroll
            for (int ww = 0; ww < 16; ++ww) s4 += s_red[tid][ww];
            fnorm[b * TFEAT + t0 + tid] = s4;
        }
    }
}

// ---------------------------------------------------------------------------
// Score: 512 threads / 8 waves per block; wave w handles N-frags {w} and
// (w<2 ? {w+8} : none). LDS Stirling-lgamma table; 2-barrier LDS softmax.
// Round-9 verified, unchanged.
// ---------------------------------------------------------------------------
__global__ __launch_bounds__(512) void score_mfma(
    const unsigned short* __restrict__ F, const unsigned short* __restrict__ Tt,
    const float* __restrict__ fnorm, const float* __restrict__ tnorm,
    const unsigned char* __restrict__ xmask,
    float* __restrict__ out)
{
    const int b  = blockIdx.y;
    const int tid = threadIdx.x;
    const int w  = tid >> 6;        // 0..7
    const int l  = tid & 63;
    const int lr = l & 15;
    const int lk = l >> 4;
    const int i0 = blockIdx.x * 16;
    const int NI = (w < 2) ? 2 : 1;

    __shared__ float s_lg[962];
    __shared__ float s_red[16][8];
    __shared__ float s_red2[16][8];

    for (int idx = tid; idx < 962; idx += 512)
        s_lg[idx] = (idx >= 1) ? lgamma_int((float)idx) : 0.0f;

    f32x4 acc[2];
#pragma unroll
    for (int ni = 0; ni < 2; ++ni) acc[ni] = {0.f, 0.f, 0.f, 0.f};

    const unsigned short* __restrict__ Fp = F + ((size_t)(b * TFEAT + i0 + lr)) * 256;
    const unsigned short* __restrict__ Tp = Tt + ((size_t)b * TTEXT) * 256;

#pragma unroll
    for (int c = 0; c < 8; ++c) {
        const int d = c * 32 + lk * 8;
        const bf16x8 a = *(const bf16x8*)(Fp + d);
#pragma unroll
        for (int ni = 0; ni < 2; ++ni) {
            if (ni < NI) {
                const int n = w + ni * 8;
                const bf16x8 bb = *(const bf16x8*)(Tp + ((size_t)(n * 16 + lr)) * 256 + d);
                acc[ni] = __builtin_amdgcn_mfma_f32_16x16x32_bf16(a, bb, acc[ni], 0, 0, 0);
            }
        }
    }

    float fn[4];
#pragma unroll
    for (int r = 0; r < 4; ++r) fn[r] = fnorm[b * TFEAT + i0 + lk * 4 + r];
    float tn[2]; bool mk[2];
#pragma unroll
    for (int ni = 0; ni < 2; ++ni) {
        if (ni < NI) {
            const int j = (w + ni * 8) * 16 + lr;
            tn[ni] = tnorm[b * TTEXT + j];
            mk[ni] = xmask[b * TTEXT + j] != 0;
        } else { tn[ni] = 0.f; mk[ni] = true; }
    }
    float sc[2][4];
#pragma unroll
    for (int ni = 0; ni < 2; ++ni)
#pragma unroll
        for (int r = 0; r < 4; ++r) {
            const float d2 = fn[r] + tn[ni] - 2.0f * acc[ni][r];
            const float sv = -sqrtf(fmaxf(d2, 0.0f));
            sc[ni][r] = mk[ni] ? -INFINITY : sv;
        }

    // pass 1: wave-local max per row
#pragma unroll
    for (int r = 0; r < 4; ++r) {
        float mx = fmaxf(sc[0][r], sc[1][r]);
        mx = fmaxf(mx, __shfl_xor(mx, 1));
        mx = fmaxf(mx, __shfl_xor(mx, 2));
        mx = fmaxf(mx, __shfl_xor(mx, 4));
        mx = fmaxf(mx, __shfl_xor(mx, 8));
        if (lr == 0) s_red[lk * 4 + r][w] = mx;
    }
    __syncthreads();
    // pass 2: global max + wave-local exp-sum
    float gmax[4];
#pragma unroll
    for (int r = 0; r < 4; ++r) {
        const int row = lk * 4 + r;
        float g = s_red[row][0];
#pragma unroll
        for (int ww = 1; ww < 8; ++ww) g = fmaxf(g, s_red[row][ww]);
        gmax[r] = g;
        float sm = 0.f;
#pragma unroll
        for (int ni = 0; ni < 2; ++ni)
            if (ni < NI) sm += expf(sc[ni][r] - g);
        sm += __shfl_xor(sm, 1);
        sm += __shfl_xor(sm, 2);
        sm += __shfl_xor(sm, 4);
        sm += __shfl_xor(sm, 8);
        if (lr == 0) s_red2[row][w] = sm;
    }
    __syncthreads();

    const float cst = s_lg[161] - s_lg[961] + s_lg[801];
#pragma unroll
    for (int r = 0; r < 4; ++r) {
        const int row = lk * 4 + r;
        float ssum = s_red2[row][0];
#pragma unroll
        for (int ww = 1; ww < 8; ++ww) ssum += s_red2[row][ww];
        const float lse = gmax[r] + logf(ssum);
        const int grow = i0 + row;
        const float rowterm = cst - s_lg[grow + 1] - s_lg[801 - grow];
#pragma unroll
        for (int ni = 0; ni < 2; ++ni) {
            if (ni < NI) {
                const int j = (w + ni * 8) * 16 + lr;
                const float prior = rowterm - s_lg[j + 1] - s_lg[160 - j]
                                  + s_lg[grow + j + 1] + s_lg[960 - grow - j];
                out[((size_t)(b * TFEAT + grow)) * TTEXT + j] = sc[ni][r] - lse + prior;
            }
        }
    }
}

extern "C" void kernel_launch(void* const* d_in, const int* in_sizes, int n_in,
                              void* d_out, int out_size, void* d_ws, size_t ws_size,
                              hipStream_t stream) {
    const float* text  = (const float*)d_in[0];
    const float* feats = (const float*)d_in[1];
    const unsigned char* xmask = (const unsigned char*)d_in[4];
    const float* t_w1 = (const float*)d_in[5];
    const float* t_b1 = (const float*)d_in[6];
    const float* t_w2 = (const float*)d_in[7];
    const float* t_b2 = (const float*)d_in[8];
    const float* f_w1 = (const float*)d_in[9];
    const float* f_b1 = (const float*)d_in[10];
    const float* f_w2 = (const float*)d_in[11];
    const float* f_b2 = (const float*)d_in[12];
    const float* f_w3 = (const float*)d_in[13];
    const float* f_b3 = (const float*)d_in[14];
    float* out = (float*)d_out;

    char* wp = (char*)d_ws;
    auto alloc = [&](size_t bytes) -> void* {
        void* p = wp; wp += (bytes + 255) & ~(size_t)255; return p;
    };
    unsigned short* wb_t1 = (unsigned short*)alloc(196608 * 2);
    unsigned short* wb_t2 = (unsigned short*)alloc(65536 * 2);
    unsigned short* wb_f1 = (unsigned short*)alloc(73728 * 2);
    unsigned short* wb_f2 = (unsigned short*)alloc(196608 * 2);
    unsigned short* wb_f3 = (unsigned short*)alloc(65536 * 2);
    unsigned short* tB = (unsigned short*)alloc((size_t)NB * TTEXT * 256 * 2);
    unsigned short* fC = (unsigned short*)alloc((size_t)NB * TFEAT * 256 * 2);
    float* fnorm = (float*)alloc((size_t)NB * TFEAT * 4);
    float* tnorm = (float*)alloc((size_t)NB * TTEXT * 4);

    prep_kernel<<<2336, 256, 0, stream>>>(
        t_w1, t_w2, f_w1, f_w2, f_w3, wb_t1, wb_t2, wb_f1, wb_f2, wb_f3);

    stems_kernel<<<240, 1024, 0, stream>>>(
        text, feats,
        wb_t1, t_b1, wb_t2, t_b2,
        wb_f1, f_b1, wb_f2, f_b2, wb_f3, f_b3,
        tB, tnorm, fC, fnorm);

    score_mfma<<<dim3(50, NB), 512, 0, stream>>>(fC, tB, fnorm, tnorm, xmask, out);
}

// Round 13
// 30.598 us; speedup vs baseline: 3.8415x; 1.0453x over previous
//
#include <hip/hip_runtime.h>
#include <math.h>

#define NB 4
#define TTEXT 160
#define TFEAT 800

typedef __bf16 bf16x8 __attribute__((ext_vector_type(8)));
typedef float f32x4 __attribute__((ext_vector_type(4)));

__device__ inline unsigned short f2bf(float f) {
    unsigned int u = __builtin_bit_cast(unsigned int, f);
    unsigned int r = u + 0x7fffu + ((u >> 16) & 1u);
    return (unsigned short)(r >> 16);
}
__device__ inline float bf2f(unsigned short h) {
    unsigned int u = ((unsigned int)h) << 16;
    return __builtin_bit_cast(float, u);
}

// f32 lgamma for integer arguments n>=1 (Stirling, n<8 promoted by 8).
__device__ inline float lgamma_int(float nf) {
    float z = nf, corr = 0.0f;
    if (nf < 8.0f) {
        const float p = nf * (nf + 1.0f) * (nf + 2.0f) * (nf + 3.0f)
                      * (nf + 4.0f) * (nf + 5.0f) * (nf + 6.0f) * (nf + 7.0f);
        z = nf + 8.0f;
        corr = logf(p);
    }
    const float lz = logf(z);
    const float iz = 1.0f / z;
    const float s = (z - 0.5f) * lz - z + 0.918938533f
                  + iz * (0.0833333333f - iz * iz * 0.00277777778f);
    return s - corr;
}

// async global->LDS, 16B per lane; LDS dest must be wave-uniform base.
__device__ __forceinline__ void gll16(const unsigned short* g, unsigned short* l) {
    __builtin_amdgcn_global_load_lds(
        (const __attribute__((address_space(1))) void*)g,
        (__attribute__((address_space(3))) void*)l, 16, 0, 0);
}
__device__ __forceinline__ unsigned short* bufsel(
    unsigned short* a, unsigned short* b, unsigned short* c_, int i) {
    return (i == 0) ? a : (i == 1) ? b : c_;
}

// wave w stages its 512-elem (1KB) slice of 16KB chunk c into buf.
// Per-wave slices are private: wave w writes/reads only buf+(w<<9).
#define STAGE(W, c, buf) gll16((W) + ((size_t)(c) << 13) + (w << 9) + (l << 3), (buf) + (w << 9))
#define WAITV(n) asm volatile("s_waitcnt vmcnt(" #n ")" ::: "memory")

// ---------------------------------------------------------------------------
// Prep: flat exact grid (2336 blocks x 256). Weight transform into
// B-fragment-native layout Wb[c][co][q]. Round-9 verified, unchanged.
// ---------------------------------------------------------------------------
__global__ __launch_bounds__(256) void prep_kernel(
    const float* __restrict__ tw1, const float* __restrict__ tw2,
    const float* __restrict__ fw1, const float* __restrict__ fw2,
    const float* __restrict__ fw3,
    unsigned short* __restrict__ wb_t1, unsigned short* __restrict__ wb_t2,
    unsigned short* __restrict__ wb_f1, unsigned short* __restrict__ wb_f2,
    unsigned short* __restrict__ wb_f3)
{
    const int u = blockIdx.x * 256 + threadIdx.x;
    int rem = u;
    int CIN, CINP, K; const float* src; unsigned short* dst;
    if (rem < 196608)                  { CIN = 256; CINP = 256; K = 3; src = tw1; dst = wb_t1; }
    else if ((rem -= 196608) < 65536)  { CIN = 256; CINP = 256; K = 1; src = tw2; dst = wb_t2; }
    else if ((rem -= 65536) < 73728)   { CIN = 80;  CINP = 96;  K = 3; src = fw1; dst = wb_f1; }
    else if ((rem -= 73728) < 196608)  { CIN = 256; CINP = 256; K = 3; src = fw2; dst = wb_f2; }
    else { rem -= 196608;                CIN = 256; CINP = 256; K = 1; src = fw3; dst = wb_f3; }
    const int q = rem & 31, coc = rem >> 5, co = coc & 255, c = coc >> 8;
    const int cpk = CINP / 32, k = c / cpk, ci = (c % cpk) * 32 + q;
    const float v = (ci < CIN) ? src[((size_t)co * CIN + ci) * K + k] : 0.0f;
    dst[rem] = f2bf(v);
}

// ---------------------------------------------------------------------------
// Fused stems, 1024 threads = 16 waves; wave w owns 16 output channels.
// Round-12 math/pipeline unchanged; the first two weight STAGEs of every
// layer are HOISTED before the preceding barrier (the barrier's implicit
// vmcnt(0) drain guarantees they have landed) so each layer starts with
// its first chunks already resident instead of paying 2 serial latencies.
// ---------------------------------------------------------------------------
__global__ __launch_bounds__(1024) void stems_kernel(
    const float* __restrict__ text, const float* __restrict__ feats,
    const unsigned short* __restrict__ wt1, const float* __restrict__ bt1,
    const unsigned short* __restrict__ wt2, const float* __restrict__ bt2,
    const unsigned short* __restrict__ wf1, const float* __restrict__ bf1v,
    const unsigned short* __restrict__ wf2, const float* __restrict__ bf2v,
    const unsigned short* __restrict__ wf3, const float* __restrict__ bf3v,
    unsigned short* __restrict__ tB, float* __restrict__ tnorm,
    unsigned short* __restrict__ fC, float* __restrict__ fnorm)
{
    __shared__ __align__(16) unsigned short s[11056];
    __shared__ __align__(16) unsigned short ws0[8192];
    __shared__ __align__(16) unsigned short ws1[8192];
    __shared__ __align__(16) unsigned short ws2[8192];
    __shared__ float s_red[16][16];
    const int tid = threadIdx.x;
    const int w  = tid >> 6;        // 0..15
    const int l  = tid & 63;
    const int lr = l & 15;
    const int lk = l >> 4;
    const int co0 = w * 16;         // 16 channels per wave
    const int koff = lk * 8;
    const int bid = blockIdx.x;

    if (bid < 40) {
        // ------------------------- text stem -------------------------
        const int b  = bid & 3;
        const int t0 = (bid >> 2) << 4;
        unsigned short* s_in  = s;          // [18][264]
        unsigned short* s_mid = s + 4752;   // [16][264]

        // prefetch t1 chunks 0/1 (overlaps input staging; barrier drains)
        STAGE(wt1, 0, ws0);
        STAGE(wt1, 1, ws1);

        for (int idx = tid; idx < 18 * 64; idx += 1024) {
            const int r = idx >> 6, c4 = idx & 63;
            const int x = t0 - 1 + r;
            float4 v = {0.f, 0.f, 0.f, 0.f};
            if (x >= 0 && x < TTEXT)
                v = *(const float4*)(text + ((size_t)(b * TTEXT + x)) * 256 + c4 * 4);
            unsigned short* p = s_in + r * 264 + c4 * 4;
            p[0] = f2bf(v.x); p[1] = f2bf(v.y); p[2] = f2bf(v.z); p[3] = f2bf(v.w);
        }
        __syncthreads();

        // t1: K=3, CIN=256 -> 24 chunks (staged weights)
        f32x4 acc = {0.f, 0.f, 0.f, 0.f};
#pragma unroll 3
        for (int c = 0; c < 24; ++c) {
            unsigned short* cur = bufsel(ws0, ws1, ws2, c % 3);
            if (c < 22) {
                unsigned short* nxt = bufsel(ws0, ws1, ws2, (c + 2) % 3);
                STAGE(wt1, c + 2, nxt);
                WAITV(2);
            } else if (c == 22) { WAITV(1); } else { WAITV(0); }
            const int k  = c >> 3;
            const int ci = ((c & 7) << 5) + koff;
            const bf16x8 a = *(const bf16x8*)(s_in + (lr + k) * 264 + ci);
            const bf16x8 bb = *(const bf16x8*)(cur + (w << 9) + lr * 32 + lk * 8);
            acc = __builtin_amdgcn_mfma_f32_16x16x32_bf16(a, bb, acc, 0, 0, 0);
        }
        // prefetch t2 chunks 0/1 (lands during epilogue + barrier)
        STAGE(wt2, 0, ws0);
        STAGE(wt2, 1, ws1);
        {
            const float bv = bt1[co0 + lr];
#pragma unroll
            for (int r = 0; r < 4; ++r)
                s_mid[(lk * 4 + r) * 264 + co0 + lr] = f2bf(fmaxf(acc[r] + bv, 0.f));
        }
        __syncthreads();

        // t2: K=1 -> 8 chunks (staged weights)
        f32x4 a2 = {0.f, 0.f, 0.f, 0.f};
#pragma unroll
        for (int c = 0; c < 8; ++c) {
            unsigned short* cur = bufsel(ws0, ws1, ws2, c % 3);
            if (c < 6) {
                unsigned short* nxt = bufsel(ws0, ws1, ws2, (c + 2) % 3);
                STAGE(wt2, c + 2, nxt);
                WAITV(2);
            } else if (c == 6) { WAITV(1); } else { WAITV(0); }
            const bf16x8 a = *(const bf16x8*)(s_mid + lr * 264 + (c << 5) + koff);
            const bf16x8 bb = *(const bf16x8*)(cur + (w << 9) + lr * 32 + lk * 8);
            a2 = __builtin_amdgcn_mfma_f32_16x16x32_bf16(a, bb, a2, 0, 0, 0);
        }
        const float bv2 = bt2[co0 + lr];
#pragma unroll
        for (int r = 0; r < 4; ++r) {
            const int row = lk * 4 + r;
            const unsigned short h = f2bf(a2[r] + bv2);
            tB[((size_t)(b * TTEXT + t0 + row)) * 256 + co0 + lr] = h;
            const float vq = bf2f(h);
            float np = vq * vq;
            np += __shfl_xor(np, 1);
            np += __shfl_xor(np, 2);
            np += __shfl_xor(np, 4);
            np += __shfl_xor(np, 8);
            if (lr == 0) s_red[row][w] = np;
        }
        __syncthreads();
        if (tid < 16) {
            float s4 = 0.f;
#pragma unroll
            for (int ww = 0; ww < 16; ++ww) s4 += s_red[tid][ww];
            tnorm[b * TTEXT + t0 + tid] = s4;
        }
    } else {
        // ------------------------- feats stem -------------------------
        const int fb = bid - 40;
        const int b  = fb & 3;
        const int t0 = (fb >> 2) << 4;
        unsigned short* s_fin = s;          // [20][104]
        unsigned short* s_b1  = s + 2080;   // [18][264]
        unsigned short* s_b2  = s + 6832;   // [16][264]

        // prefetch f1 chunks 0/1 (overlaps input staging; barrier drains)
        STAGE(wf1, 0, ws0);
        STAGE(wf1, 1, ws1);

        for (int idx = tid; idx < 20 * 24; idx += 1024) {
            const int r  = idx / 24, c4 = idx - r * 24;
            const int ch = c4 * 4;
            const int x  = t0 - 2 + r;
            float4 v = {0.f, 0.f, 0.f, 0.f};
            if (ch < 80 && x >= 0 && x < TFEAT)
                v = *(const float4*)(feats + ((size_t)(b * TFEAT + x)) * 80 + ch);
            unsigned short* p = s_fin + r * 104 + ch;
            p[0] = f2bf(v.x); p[1] = f2bf(v.y); p[2] = f2bf(v.z); p[3] = f2bf(v.w);
        }
        __syncthreads();

        // f1: K=3, CINP=96 -> 9 chunks (staged); 18 output rows (2 M-frags)
        f32x4 acc1[2];
#pragma unroll
        for (int m = 0; m < 2; ++m) acc1[m] = {0.f, 0.f, 0.f, 0.f};
#pragma unroll
        for (int c = 0; c < 9; ++c) {
            unsigned short* cur = bufsel(ws0, ws1, ws2, c % 3);
            if (c < 7) {
                unsigned short* nxt = bufsel(ws0, ws1, ws2, (c + 2) % 3);
                STAGE(wf1, c + 2, nxt);
                WAITV(2);
            } else if (c == 7) { WAITV(1); } else { WAITV(0); }
            const int k  = c / 3;
            const int ci = (c - k * 3) * 32 + koff;
            const bf16x8 bb = *(const bf16x8*)(cur + (w << 9) + lr * 32 + lk * 8);
#pragma unroll
            for (int m = 0; m < 2; ++m) {
                int rr = m * 16 + lr + k;
                if (rr > 19) rr = 19;   // clamp; rows >=18 masked at write
                const bf16x8 a = *(const bf16x8*)(s_fin + rr * 104 + ci);
                acc1[m] = __builtin_amdgcn_mfma_f32_16x16x32_bf16(a, bb, acc1[m], 0, 0, 0);
            }
        }
        // prefetch f2 chunks 0/1 (lands during epilogue + barrier)
        STAGE(wf2, 0, ws0);
        STAGE(wf2, 1, ws1);
        {
            const float bv = bf1v[co0 + lr];
#pragma unroll
            for (int m = 0; m < 2; ++m)
#pragma unroll
                for (int r = 0; r < 4; ++r) {
                    const int i = m * 16 + lk * 4 + r;
                    if (i < 18)
                        s_b1[i * 264 + co0 + lr] = f2bf(fmaxf(acc1[m][r] + bv, 0.f));
                }
        }
        __syncthreads();

        // f2: K=3, CIN=256 -> 24 chunks (staged)
        f32x4 acc2 = {0.f, 0.f, 0.f, 0.f};
#pragma unroll 3
        for (int c = 0; c < 24; ++c) {
            unsigned short* cur = bufsel(ws0, ws1, ws2, c % 3);
            if (c < 22) {
                unsigned short* nxt = bufsel(ws0, ws1, ws2, (c + 2) % 3);
                STAGE(wf2, c + 2, nxt);
                WAITV(2);
            } else if (c == 22) { WAITV(1); } else { WAITV(0); }
            const int k  = c >> 3;
            const int ci = ((c & 7) << 5) + koff;
            const bf16x8 a = *(const bf16x8*)(s_b1 + (lr + k) * 264 + ci);
            const bf16x8 bb = *(const bf16x8*)(cur + (w << 9) + lr * 32 + lk * 8);
            acc2 = __builtin_amdgcn_mfma_f32_16x16x32_bf16(a, bb, acc2, 0, 0, 0);
        }
        // prefetch f3 chunks 0/1 (lands during epilogue + barrier)
        STAGE(wf3, 0, ws0);
        STAGE(wf3, 1, ws1);
        {
            const float bv = bf2v[co0 + lr];
#pragma unroll
            for (int r = 0; r < 4; ++r)
                s_b2[(lk * 4 + r) * 264 + co0 + lr] = f2bf(fmaxf(acc2[r] + bv, 0.f));
        }
        __syncthreads();

        // f3: K=1 -> 8 chunks (staged), epilogue to global + norm
        f32x4 a3 = {0.f, 0.f, 0.f, 0.f};
#pragma unroll
        for (int c = 0; c < 8; ++c) {
            unsigned short* cur = bufsel(ws0, ws1, ws2, c % 3);
            if (c < 6) {
                unsigned short* nxt = bufsel(ws0, ws1, ws2, (c + 2) % 3);
                STAGE(wf3, c + 2, nxt);
                WAITV(2);
            } else if (c == 6) { WAITV(1); } else { WAITV(0); }
            const bf16x8 a = *(const bf16x8*)(s_b2 + lr * 264 + (c << 5) + koff);
            const bf16x8 bb = *(const bf16x8*)(cur + (w << 9) + lr * 32 + lk * 8);
            a3 = __builtin_amdgcn_mfma_f32_16x16x32_bf16(a, bb, a3, 0, 0, 0);
        }
        const float bv3 = bf3v[co0 + lr];
#pragma unroll
        for (int r = 0; r < 4; ++r) {
            const int row = lk * 4 + r;
            const unsigned short h = f2bf(a3[r] + bv3);
            fC[((size_t)(b * TFEAT + t0 + row)) * 256 + co0 + lr] = h;
            const float vq = bf2f(h);
            float np = vq * vq;
            np += __shfl_xor(np, 1);
            np += __shfl_xor(np, 2);
            np += __shfl_xor(np, 4);
            np += __shfl_xor(np, 8);
            if (lr == 0) s_red[row][w] = np;
        }
        __syncthreads();
        if (tid < 16) {
            float s4 = 0.f;
#pragma unroll
            for (int ww = 0; ww < 16; ++ww) s4 += s_red[tid][ww];
            fnorm[b * TFEAT + t0 + tid] = s4;
        }
    }
}

// ---------------------------------------------------------------------------
// Score: 640 threads = 10 waves, wave w owns exactly N-frag w (balanced —
// no 2x-loaded waves). LDS Stirling-lgamma table; 2-barrier LDS softmax.
// ---------------------------------------------------------------------------
__global__ __launch_bounds__(640) void score_mfma(
    const unsigned short* __restrict__ F, const unsigned short* __restrict__ Tt,
    const float* __restrict__ fnorm, const float* __restrict__ tnorm,
    const unsigned char* __restrict__ xmask,
    float* __restrict__ out)
{
    const int b  = blockIdx.y;
    const int tid = threadIdx.x;
    const int w  = tid >> 6;        // 0..9
    const int l  = tid & 63;
    const int lr = l & 15;
    const int lk = l >> 4;
    const int i0 = blockIdx.x * 16;

    __shared__ float s_lg[962];
    __shared__ float s_red[16][10];
    __shared__ float s_red2[16][10];

    for (int idx = tid; idx < 962; idx += 640)
        s_lg[idx] = (idx >= 1) ? lgamma_int((float)idx) : 0.0f;

    f32x4 acc = {0.f, 0.f, 0.f, 0.f};

    const unsigned short* __restrict__ Fp = F + ((size_t)(b * TFEAT + i0 + lr)) * 256;
    const unsigned short* __restrict__ Tp = Tt + ((size_t)(b * TTEXT + w * 16 + lr)) * 256;

#pragma unroll
    for (int c = 0; c < 8; ++c) {
        const int d = c * 32 + lk * 8;
        const bf16x8 a = *(const bf16x8*)(Fp + d);
        const bf16x8 bb = *(const bf16x8*)(Tp + d);
        acc = __builtin_amdgcn_mfma_f32_16x16x32_bf16(a, bb, acc, 0, 0, 0);
    }

    float fn[4];
#pragma unroll
    for (int r = 0; r < 4; ++r) fn[r] = fnorm[b * TFEAT + i0 + lk * 4 + r];
    const int j = w * 16 + lr;
    const float tn = tnorm[b * TTEXT + j];
    const bool mk = xmask[b * TTEXT + j] != 0;

    float sc[4];
#pragma unroll
    for (int r = 0; r < 4; ++r) {
        const float d2 = fn[r] + tn - 2.0f * acc[r];
        const float sv = -sqrtf(fmaxf(d2, 0.0f));
        sc[r] = mk ? -INFINITY : sv;
    }

    // pass 1: wave-local max per row
#pragma unroll
    for (int r = 0; r < 4; ++r) {
        float mx = sc[r];
        mx = fmaxf(mx, __shfl_xor(mx, 1));
        mx = fmaxf(mx, __shfl_xor(mx, 2));
        mx = fmaxf(mx, __shfl_xor(mx, 4));
        mx = fmaxf(mx, __shfl_xor(mx, 8));
        if (lr == 0) s_red[lk * 4 + r][w] = mx;
    }
    __syncthreads();
    // pass 2: global max + wave-local exp-sum
    float gmax[4];
#pragma unroll
    for (int r = 0; r < 4; ++r) {
        const int row = lk * 4 + r;
        float g = s_red[row][0];
#pragma unroll
        for (int ww = 1; ww < 10; ++ww) g = fmaxf(g, s_red[row][ww]);
        gmax[r] = g;
        float sm = expf(sc[r] - g);
        sm += __shfl_xor(sm, 1);
        sm += __shfl_xor(sm, 2);
        sm += __shfl_xor(sm, 4);
        sm += __shfl_xor(sm, 8);
        if (lr == 0) s_red2[row][w] = sm;
    }
    __syncthreads();

    const float cst = s_lg[161] - s_lg[961] + s_lg[801];
#pragma unroll
    for (int r = 0; r < 4; ++r) {
        const int row = lk * 4 + r;
        float ssum = s_red2[row][0];
#pragma unroll
        for (int ww = 1; ww < 10; ++ww) ssum += s_red2[row][ww];
        const float lse = gmax[r] + logf(ssum);
        const int grow = i0 + row;
        const float rowterm = cst - s_lg[grow + 1] - s_lg[801 - grow];
        const float prior = rowterm - s_lg[j + 1] - s_lg[160 - j]
                          + s_lg[grow + j + 1] + s_lg[960 - grow - j];
        out[((size_t)(b * TFEAT + grow)) * TTEXT + j] = sc[r] - lse + prior;
    }
}

extern "C" void kernel_launch(void* const* d_in, const int* in_sizes, int n_in,
                              void* d_out, int out_size, void* d_ws, size_t ws_size,
                              hipStream_t stream) {
    const float* text  = (const float*)d_in[0];
    const float* feats = (const float*)d_in[1];
    const unsigned char* xmask = (const unsigned char*)d_in[4];
    const float* t_w1 = (const float*)d_in[5];
    const float* t_b1 = (const float*)d_in[6];
    const float* t_w2 = (const float*)d_in[7];
    const float* t_b2 = (const float*)d_in[8];
    const float* f_w1 = (const float*)d_in[9];
    const float* f_b1 = (const float*)d_in[10];
    const float* f_w2 = (const float*)d_in[11];
    const float* f_b2 = (const float*)d_in[12];
    const float* f_w3 = (const float*)d_in[13];
    const float* f_b3 = (const float*)d_in[14];
    float* out = (float*)d_out;

    char* wp = (char*)d_ws;
    auto alloc = [&](size_t bytes) -> void* {
        void* p = wp; wp += (bytes + 255) & ~(size_t)255; return p;
    };
    unsigned short* wb_t1 = (unsigned short*)alloc(196608 * 2);
    unsigned short* wb_t2 = (unsigned short*)alloc(65536 * 2);
    unsigned short* wb_f1 = (unsigned short*)alloc(73728 * 2);
    unsigned short* wb_f2 = (unsigned short*)alloc(196608 * 2);
    unsigned short* wb_f3 = (unsigned short*)alloc(65536 * 2);
    unsigned short* tB = (unsigned short*)alloc((size_t)NB * TTEXT * 256 * 2);
    unsigned short* fC = (unsigned short*)alloc((size_t)NB * TFEAT * 256 * 2);
    float* fnorm = (float*)alloc((size_t)NB * TFEAT * 4);
    float* tnorm = (float*)alloc((size_t)NB * TTEXT * 4);

    prep_kernel<<<2336, 256, 0, stream>>>(
        t_w1, t_w2, f_w1, f_w2, f_w3, wb_t1, wb_t2, wb_f1, wb_f2, wb_f3);

    stems_kernel<<<240, 1024, 0, stream>>>(
        text, feats,
        wb_t1, t_b1, wb_t2, t_b2,
        wb_f1, f_b1, wb_f2, f_b2, wb_f3, f_b3,
        tB, tnorm, fC, fnorm);

    score_mfma<<<dim3(50, NB), 640, 0, stream>>>(fC, tB, fnorm, tnorm, xmask, out);
}

// Round 14
// 30.450 us; speedup vs baseline: 3.8601x; 1.0049x over previous
//
#include <hip/hip_runtime.h>
#include <math.h>

#define NB 4
#define TTEXT 160
#define TFEAT 800

typedef __bf16 bf16x8 __attribute__((ext_vector_type(8)));
typedef float f32x4 __attribute__((ext_vector_type(4)));

__device__ inline unsigned short f2bf(float f) {
    unsigned int u = __builtin_bit_cast(unsigned int, f);
    unsigned int r = u + 0x7fffu + ((u >> 16) & 1u);
    return (unsigned short)(r >> 16);
}
__device__ inline float bf2f(unsigned short h) {
    unsigned int u = ((unsigned int)h) << 16;
    return __builtin_bit_cast(float, u);
}

// f32 lgamma for integer arguments n>=1 (Stirling, n<8 promoted by 8).
__device__ inline float lgamma_int(float nf) {
    float z = nf, corr = 0.0f;
    if (nf < 8.0f) {
        const float p = nf * (nf + 1.0f) * (nf + 2.0f) * (nf + 3.0f)
                      * (nf + 4.0f) * (nf + 5.0f) * (nf + 6.0f) * (nf + 7.0f);
        z = nf + 8.0f;
        corr = logf(p);
    }
    const float lz = logf(z);
    const float iz = 1.0f / z;
    const float s = (z - 0.5f) * lz - z + 0.918938533f
                  + iz * (0.0833333333f - iz * iz * 0.00277777778f);
    return s - corr;
}

// async global->LDS, 16B per lane; LDS dest must be wave-uniform base.
__device__ __forceinline__ void gll16(const unsigned short* g, unsigned short* l) {
    __builtin_amdgcn_global_load_lds(
        (const __attribute__((address_space(1))) void*)g,
        (__attribute__((address_space(3))) void*)l, 16, 0, 0);
}
__device__ __forceinline__ unsigned short* bufsel(
    unsigned short* a, unsigned short* b, unsigned short* c_, unsigned short* d, int i) {
    return (i == 0) ? a : (i == 1) ? b : (i == 2) ? c_ : d;
}

// wave w stages its 512-elem (1KB) slice of 16KB chunk c into buf.
// Per-wave slices are private: wave w writes/reads only buf+(w<<9).
#define STAGE(W, c, buf) gll16((W) + ((size_t)(c) << 13) + (w << 9) + (l << 3), (buf) + (w << 9))
#define WAITV(n) asm volatile("s_waitcnt vmcnt(" #n ")" ::: "memory")

// ---------------------------------------------------------------------------
// Prep: flat exact grid (2336 blocks x 256). Weight transform into
// B-fragment-native layout Wb[c][co][q]. Round-9 verified, unchanged.
// ---------------------------------------------------------------------------
__global__ __launch_bounds__(256) void prep_kernel(
    const float* __restrict__ tw1, const float* __restrict__ tw2,
    const float* __restrict__ fw1, const float* __restrict__ fw2,
    const float* __restrict__ fw3,
    unsigned short* __restrict__ wb_t1, unsigned short* __restrict__ wb_t2,
    unsigned short* __restrict__ wb_f1, unsigned short* __restrict__ wb_f2,
    unsigned short* __restrict__ wb_f3)
{
    const int u = blockIdx.x * 256 + threadIdx.x;
    int rem = u;
    int CIN, CINP, K; const float* src; unsigned short* dst;
    if (rem < 196608)                  { CIN = 256; CINP = 256; K = 3; src = tw1; dst = wb_t1; }
    else if ((rem -= 196608) < 65536)  { CIN = 256; CINP = 256; K = 1; src = tw2; dst = wb_t2; }
    else if ((rem -= 65536) < 73728)   { CIN = 80;  CINP = 96;  K = 3; src = fw1; dst = wb_f1; }
    else if ((rem -= 73728) < 196608)  { CIN = 256; CINP = 256; K = 3; src = fw2; dst = wb_f2; }
    else { rem -= 196608;                CIN = 256; CINP = 256; K = 1; src = fw3; dst = wb_f3; }
    const int q = rem & 31, coc = rem >> 5, co = coc & 255, c = coc >> 8;
    const int cpk = CINP / 32, k = c / cpk, ci = (c % cpk) * 32 + q;
    const float v = (ci < CIN) ? src[((size_t)co * CIN + ci) * K + k] : 0.0f;
    dst[rem] = f2bf(v);
}

// ---------------------------------------------------------------------------
// Fused stems, 1024 threads = 16 waves; wave w owns 16 output channels.
// Round-13 math/pipeline unchanged; weight ring deepened to 4 buffers with
// depth-3 prefetch (48KB in flight vs 32KB) to cover L2 latency through
// the whole chunk stream. Prologue stages 3 chunks, hoisted before the
// preceding barrier (its vmcnt(0) drain guarantees residency).
// ---------------------------------------------------------------------------
__global__ __launch_bounds__(1024) void stems_kernel(
    const float* __restrict__ text, const float* __restrict__ feats,
    const unsigned short* __restrict__ wt1, const float* __restrict__ bt1,
    const unsigned short* __restrict__ wt2, const float* __restrict__ bt2,
    const unsigned short* __restrict__ wf1, const float* __restrict__ bf1v,
    const unsigned short* __restrict__ wf2, const float* __restrict__ bf2v,
    const unsigned short* __restrict__ wf3, const float* __restrict__ bf3v,
    unsigned short* __restrict__ tB, float* __restrict__ tnorm,
    unsigned short* __restrict__ fC, float* __restrict__ fnorm)
{
    __shared__ __align__(16) unsigned short s[11056];
    __shared__ __align__(16) unsigned short ws0[8192];
    __shared__ __align__(16) unsigned short ws1[8192];
    __shared__ __align__(16) unsigned short ws2[8192];
    __shared__ __align__(16) unsigned short ws3[8192];
    __shared__ float s_red[16][16];
    const int tid = threadIdx.x;
    const int w  = tid >> 6;        // 0..15
    const int l  = tid & 63;
    const int lr = l & 15;
    const int lk = l >> 4;
    const int co0 = w * 16;         // 16 channels per wave
    const int koff = lk * 8;
    const int bid = blockIdx.x;

    if (bid < 40) {
        // ------------------------- text stem -------------------------
        const int b  = bid & 3;
        const int t0 = (bid >> 2) << 4;
        unsigned short* s_in  = s;          // [18][264]
        unsigned short* s_mid = s + 4752;   // [16][264]

        // prefetch t1 chunks 0/1/2 (overlaps input staging; barrier drains)
        STAGE(wt1, 0, ws0);
        STAGE(wt1, 1, ws1);
        STAGE(wt1, 2, ws2);

        for (int idx = tid; idx < 18 * 64; idx += 1024) {
            const int r = idx >> 6, c4 = idx & 63;
            const int x = t0 - 1 + r;
            float4 v = {0.f, 0.f, 0.f, 0.f};
            if (x >= 0 && x < TTEXT)
                v = *(const float4*)(text + ((size_t)(b * TTEXT + x)) * 256 + c4 * 4);
            unsigned short* p = s_in + r * 264 + c4 * 4;
            p[0] = f2bf(v.x); p[1] = f2bf(v.y); p[2] = f2bf(v.z); p[3] = f2bf(v.w);
        }
        __syncthreads();

        // t1: K=3, CIN=256 -> 24 chunks (staged weights, depth-3 ring)
        f32x4 acc = {0.f, 0.f, 0.f, 0.f};
#pragma unroll 4
        for (int c = 0; c < 24; ++c) {
            unsigned short* cur = bufsel(ws0, ws1, ws2, ws3, c & 3);
            if (c < 21) {
                unsigned short* nxt = bufsel(ws0, ws1, ws2, ws3, (c + 3) & 3);
                STAGE(wt1, c + 3, nxt);
                WAITV(3);
            } else if (c == 21) { WAITV(2); }
            else if (c == 22)   { WAITV(1); }
            else                { WAITV(0); }
            const int k  = c >> 3;
            const int ci = ((c & 7) << 5) + koff;
            const bf16x8 a = *(const bf16x8*)(s_in + (lr + k) * 264 + ci);
            const bf16x8 bb = *(const bf16x8*)(cur + (w << 9) + lr * 32 + lk * 8);
            acc = __builtin_amdgcn_mfma_f32_16x16x32_bf16(a, bb, acc, 0, 0, 0);
        }
        // prefetch t2 chunks 0/1/2 (lands during epilogue + barrier)
        STAGE(wt2, 0, ws0);
        STAGE(wt2, 1, ws1);
        STAGE(wt2, 2, ws2);
        {
            const float bv = bt1[co0 + lr];
#pragma unroll
            for (int r = 0; r < 4; ++r)
                s_mid[(lk * 4 + r) * 264 + co0 + lr] = f2bf(fmaxf(acc[r] + bv, 0.f));
        }
        __syncthreads();

        // t2: K=1 -> 8 chunks (staged weights)
        f32x4 a2 = {0.f, 0.f, 0.f, 0.f};
#pragma unroll
        for (int c = 0; c < 8; ++c) {
            unsigned short* cur = bufsel(ws0, ws1, ws2, ws3, c & 3);
            if (c < 5) {
                unsigned short* nxt = bufsel(ws0, ws1, ws2, ws3, (c + 3) & 3);
                STAGE(wt2, c + 3, nxt);
                WAITV(3);
            } else if (c == 5) { WAITV(2); }
            else if (c == 6)   { WAITV(1); }
            else               { WAITV(0); }
            const bf16x8 a = *(const bf16x8*)(s_mid + lr * 264 + (c << 5) + koff);
            const bf16x8 bb = *(const bf16x8*)(cur + (w << 9) + lr * 32 + lk * 8);
            a2 = __builtin_amdgcn_mfma_f32_16x16x32_bf16(a, bb, a2, 0, 0, 0);
        }
        const float bv2 = bt2[co0 + lr];
#pragma unroll
        for (int r = 0; r < 4; ++r) {
            const int row = lk * 4 + r;
            const unsigned short h = f2bf(a2[r] + bv2);
            tB[((size_t)(b * TTEXT + t0 + row)) * 256 + co0 + lr] = h;
            const float vq = bf2f(h);
            float np = vq * vq;
            np += __shfl_xor(np, 1);
            np += __shfl_xor(np, 2);
            np += __shfl_xor(np, 4);
            np += __shfl_xor(np, 8);
            if (lr == 0) s_red[row][w] = np;
        }
        __syncthreads();
        if (tid < 16) {
            float s4 = 0.f;
#pragma unroll
            for (int ww = 0; ww < 16; ++ww) s4 += s_red[tid][ww];
            tnorm[b * TTEXT + t0 + tid] = s4;
        }
    } else {
        // ------------------------- feats stem -------------------------
        const int fb = bid - 40;
        const int b  = fb & 3;
        const int t0 = (fb >> 2) << 4;
        unsigned short* s_fin = s;          // [20][104]
        unsigned short* s_b1  = s + 2080;   // [18][264]
        unsigned short* s_b2  = s + 6832;   // [16][264]

        // prefetch f1 chunks 0/1/2 (overlaps input staging; barrier drains)
        STAGE(wf1, 0, ws0);
        STAGE(wf1, 1, ws1);
        STAGE(wf1, 2, ws2);

        for (int idx = tid; idx < 20 * 24; idx += 1024) {
            const int r  = idx / 24, c4 = idx - r * 24;
            const int ch = c4 * 4;
            const int x  = t0 - 2 + r;
            float4 v = {0.f, 0.f, 0.f, 0.f};
            if (ch < 80 && x >= 0 && x < TFEAT)
                v = *(const float4*)(feats + ((size_t)(b * TFEAT + x)) * 80 + ch);
            unsigned short* p = s_fin + r * 104 + ch;
            p[0] = f2bf(v.x); p[1] = f2bf(v.y); p[2] = f2bf(v.z); p[3] = f2bf(v.w);
        }
        __syncthreads();

        // f1: K=3, CINP=96 -> 9 chunks (staged); 18 output rows (2 M-frags)
        f32x4 acc1[2];
#pragma unroll
        for (int m = 0; m < 2; ++m) acc1[m] = {0.f, 0.f, 0.f, 0.f};
#pragma unroll
        for (int c = 0; c < 9; ++c) {
            unsigned short* cur = bufsel(ws0, ws1, ws2, ws3, c & 3);
            if (c < 6) {
                unsigned short* nxt = bufsel(ws0, ws1, ws2, ws3, (c + 3) & 3);
                STAGE(wf1, c + 3, nxt);
                WAITV(3);
            } else if (c == 6) { WAITV(2); }
            else if (c == 7)   { WAITV(1); }
            else               { WAITV(0); }
            const int k  = c / 3;
            const int ci = (c - k * 3) * 32 + koff;
            const bf16x8 bb = *(const bf16x8*)(cur + (w << 9) + lr * 32 + lk * 8);
#pragma unroll
            for (int m = 0; m < 2; ++m) {
                int rr = m * 16 + lr + k;
                if (rr > 19) rr = 19;   // clamp; rows >=18 masked at write
                const bf16x8 a = *(const bf16x8*)(s_fin + rr * 104 + ci);
                acc1[m] = __builtin_amdgcn_mfma_f32_16x16x32_bf16(a, bb, acc1[m], 0, 0, 0);
            }
        }
        // prefetch f2 chunks 0/1/2 (lands during epilogue + barrier)
        STAGE(wf2, 0, ws0);
        STAGE(wf2, 1, ws1);
        STAGE(wf2, 2, ws2);
        {
            const float bv = bf1v[co0 + lr];
#pragma unroll
            for (int m = 0; m < 2; ++m)
#pragma unroll
                for (int r = 0; r < 4; ++r) {
                    const int i = m * 16 + lk * 4 + r;
                    if (i < 18)
                        s_b1[i * 264 + co0 + lr] = f2bf(fmaxf(acc1[m][r] + bv, 0.f));
                }
        }
        __syncthreads();

        // f2: K=3, CIN=256 -> 24 chunks (staged, depth-3 ring)
        f32x4 acc2 = {0.f, 0.f, 0.f, 0.f};
#pragma unroll 4
        for (int c = 0; c < 24; ++c) {
            unsigned short* cur = bufsel(ws0, ws1, ws2, ws3, c & 3);
            if (c < 21) {
                unsigned short* nxt = bufsel(ws0, ws1, ws2, ws3, (c + 3) & 3);
                STAGE(wf2, c + 3, nxt);
                WAITV(3);
            } else if (c == 21) { WAITV(2); }
            else if (c == 22)   { WAITV(1); }
            else                { WAITV(0); }
            const int k  = c >> 3;
            const int ci = ((c & 7) << 5) + koff;
            const bf16x8 a = *(const bf16x8*)(s_b1 + (lr + k) * 264 + ci);
            const bf16x8 bb = *(const bf16x8*)(cur + (w << 9) + lr * 32 + lk * 8);
            acc2 = __builtin_amdgcn_mfma_f32_16x16x32_bf16(a, bb, acc2, 0, 0, 0);
        }
        // prefetch f3 chunks 0/1/2 (lands during epilogue + barrier)
        STAGE(wf3, 0, ws0);
        STAGE(wf3, 1, ws1);
        STAGE(wf3, 2, ws2);
        {
            const float bv = bf2v[co0 + lr];
#pragma unroll
            for (int r = 0; r < 4; ++r)
                s_b2[(lk * 4 + r) * 264 + co0 + lr] = f2bf(fmaxf(acc2[r] + bv, 0.f));
        }
        __syncthreads();

        // f3: K=1 -> 8 chunks (staged), epilogue to global + norm
        f32x4 a3 = {0.f, 0.f, 0.f, 0.f};
#pragma unroll
        for (int c = 0; c < 8; ++c) {
            unsigned short* cur = bufsel(ws0, ws1, ws2, ws3, c & 3);
            if (c < 5) {
                unsigned short* nxt = bufsel(ws0, ws1, ws2, ws3, (c + 3) & 3);
                STAGE(wf3, c + 3, nxt);
                WAITV(3);
            } else if (c == 5) { WAITV(2); }
            else if (c == 6)   { WAITV(1); }
            else               { WAITV(0); }
            const bf16x8 a = *(const bf16x8*)(s_b2 + lr * 264 + (c << 5) + koff);
            const bf16x8 bb = *(const bf16x8*)(cur + (w << 9) + lr * 32 + lk * 8);
            a3 = __builtin_amdgcn_mfma_f32_16x16x32_bf16(a, bb, a3, 0, 0, 0);
        }
        const float bv3 = bf3v[co0 + lr];
#pragma unroll
        for (int r = 0; r < 4; ++r) {
            const int row = lk * 4 + r;
            const unsigned short h = f2bf(a3[r] + bv3);
            fC[((size_t)(b * TFEAT + t0 + row)) * 256 + co0 + lr] = h;
            const float vq = bf2f(h);
            float np = vq * vq;
            np += __shfl_xor(np, 1);
            np += __shfl_xor(np, 2);
            np += __shfl_xor(np, 4);
            np += __shfl_xor(np, 8);
            if (lr == 0) s_red[row][w] = np;
        }
        __syncthreads();
        if (tid < 16) {
            float s4 = 0.f;
#pragma unroll
            for (int ww = 0; ww < 16; ++ww) s4 += s_red[tid][ww];
            fnorm[b * TFEAT + t0 + tid] = s4;
        }
    }
}

// ---------------------------------------------------------------------------
// Score: 640 threads = 10 waves, wave w owns exactly N-frag w (balanced).
// LDS Stirling-lgamma table; 2-barrier LDS softmax. Round-13 verified.
// ---------------------------------------------------------------------------
__global__ __launch_bounds__(640) void score_mfma(
    const unsigned short* __restrict__ F, const unsigned short* __restrict__ Tt,
    const float* __restrict__ fnorm, const float* __restrict__ tnorm,
    const unsigned char* __restrict__ xmask,
    float* __restrict__ out)
{
    const int b  = blockIdx.y;
    const int tid = threadIdx.x;
    const int w  = tid >> 6;        // 0..9
    const int l  = tid & 63;
    const int lr = l & 15;
    const int lk = l >> 4;
    const int i0 = blockIdx.x * 16;

    __shared__ float s_lg[962];
    __shared__ float s_red[16][10];
    __shared__ float s_red2[16][10];

    for (int idx = tid; idx < 962; idx += 640)
        s_lg[idx] = (idx >= 1) ? lgamma_int((float)idx) : 0.0f;

    f32x4 acc = {0.f, 0.f, 0.f, 0.f};

    const unsigned short* __restrict__ Fp = F + ((size_t)(b * TFEAT + i0 + lr)) * 256;
    const unsigned short* __restrict__ Tp = Tt + ((size_t)(b * TTEXT + w * 16 + lr)) * 256;

#pragma unroll
    for (int c = 0; c < 8; ++c) {
        const int d = c * 32 + lk * 8;
        const bf16x8 a = *(const bf16x8*)(Fp + d);
        const bf16x8 bb = *(const bf16x8*)(Tp + d);
        acc = __builtin_amdgcn_mfma_f32_16x16x32_bf16(a, bb, acc, 0, 0, 0);
    }

    float fn[4];
#pragma unroll
    for (int r = 0; r < 4; ++r) fn[r] = fnorm[b * TFEAT + i0 + lk * 4 + r];
    const int j = w * 16 + lr;
    const float tn = tnorm[b * TTEXT + j];
    const bool mk = xmask[b * TTEXT + j] != 0;

    float sc[4];
#pragma unroll
    for (int r = 0; r < 4; ++r) {
        const float d2 = fn[r] + tn - 2.0f * acc[r];
        const float sv = -sqrtf(fmaxf(d2, 0.0f));
        sc[r] = mk ? -INFINITY : sv;
    }

    // pass 1: wave-local max per row
#pragma unroll
    for (int r = 0; r < 4; ++r) {
        float mx = sc[r];
        mx = fmaxf(mx, __shfl_xor(mx, 1));
        mx = fmaxf(mx, __shfl_xor(mx, 2));
        mx = fmaxf(mx, __shfl_xor(mx, 4));
        mx = fmaxf(mx, __shfl_xor(mx, 8));
        if (lr == 0) s_red[lk * 4 + r][w] = mx;
    }
    __syncthreads();
    // pass 2: global max + wave-local exp-sum
    float gmax[4];
#pragma unroll
    for (int r = 0; r < 4; ++r) {
        const int row = lk * 4 + r;
        float g = s_red[row][0];
#pragma unroll
        for (int ww = 1; ww < 10; ++ww) g = fmaxf(g, s_red[row][ww]);
        gmax[r] = g;
        float sm = expf(sc[r] - g);
        sm += __shfl_xor(sm, 1);
        sm += __shfl_xor(sm, 2);
        sm += __shfl_xor(sm, 4);
        sm += __shfl_xor(sm, 8);
        if (lr == 0) s_red2[row][w] = sm;
    }
    __syncthreads();

    const float cst = s_lg[161] - s_lg[961] + s_lg[801];
#pragma unroll
    for (int r = 0; r < 4; ++r) {
        const int row = lk * 4 + r;
        float ssum = s_red2[row][0];
#pragma unroll
        for (int ww = 1; ww < 10; ++ww) ssum += s_red2[row][ww];
        const float lse = gmax[r] + logf(ssum);
        const int grow = i0 + row;
        const float rowterm = cst - s_lg[grow + 1] - s_lg[801 - grow];
        const float prior = rowterm - s_lg[j + 1] - s_lg[160 - j]
                          + s_lg[grow + j + 1] + s_lg[960 - grow - j];
        out[((size_t)(b * TFEAT + grow)) * TTEXT + j] = sc[r] - lse + prior;
    }
}

extern "C" void kernel_launch(void* const* d_in, const int* in_sizes, int n_in,
                              void* d_out, int out_size, void* d_ws, size_t ws_size,
                              hipStream_t stream) {
    const float* text  = (const float*)d_in[0];
    const float* feats = (const float*)d_in[1];
    const unsigned char* xmask = (const unsigned char*)d_in[4];
    const float* t_w1 = (const float*)d_in[5];
    const float* t_b1 = (const float*)d_in[6];
    const float* t_w2 = (const float*)d_in[7];
    const float* t_b2 = (const float*)d_in[8];
    const float* f_w1 = (const float*)d_in[9];
    const float* f_b1 = (const float*)d_in[10];
    const float* f_w2 = (const float*)d_in[11];
    const float* f_b2 = (const float*)d_in[12];
    const float* f_w3 = (const float*)d_in[13];
    const float* f_b3 = (const float*)d_in[14];
    float* out = (float*)d_out;

    char* wp = (char*)d_ws;
    auto alloc = [&](size_t bytes) -> void* {
        void* p = wp; wp += (bytes + 255) & ~(size_t)255; return p;
    };
    unsigned short* wb_t1 = (unsigned short*)alloc(196608 * 2);
    unsigned short* wb_t2 = (unsigned short*)alloc(65536 * 2);
    unsigned short* wb_f1 = (unsigned short*)alloc(73728 * 2);
    unsigned short* wb_f2 = (unsigned short*)alloc(196608 * 2);
    unsigned short* wb_f3 = (unsigned short*)alloc(65536 * 2);
    unsigned short* tB = (unsigned short*)alloc((size_t)NB * TTEXT * 256 * 2);
    unsigned short* fC = (unsigned short*)alloc((size_t)NB * TFEAT * 256 * 2);
    float* fnorm = (float*)alloc((size_t)NB * TFEAT * 4);
    float* tnorm = (float*)alloc((size_t)NB * TTEXT * 4);

    prep_kernel<<<2336, 256, 0, stream>>>(
        t_w1, t_w2, f_w1, f_w2, f_w3, wb_t1, wb_t2, wb_f1, wb_f2, wb_f3);

    stems_kernel<<<240, 1024, 0, stream>>>(
        text, feats,
        wb_t1, t_b1, wb_t2, t_b2,
        wb_f1, f_b1, wb_f2, f_b2, wb_f3, f_b3,
        tB, tnorm, fC, fnorm);

    score_mfma<<<dim3(50, NB), 640, 0, stream>>>(fC, tB, fnorm, tnorm, xmask, out);
}